// Round 10
// baseline (439.651 us; speedup 1.0000x reference)
//
#include <hip/hip_runtime.h>
#include <hip/hip_bf16.h>
#include <cstdint>

#define DEV static __device__ __forceinline__

typedef unsigned short u16;
typedef unsigned int u32;
typedef __attribute__((ext_vector_type(8))) short short8;
typedef __attribute__((ext_vector_type(4))) float f32x4;

constexpr int Bn = 2, Ln = 2048, Dn = 2048, Hn = 16;
constexpr int Mrows = Bn * Ln;          // 4096
constexpr int CHK = 64, NCK = Ln / CHK; // chunk=64, 32 chunks/seq
constexpr int NCHUNKS = Bn * Hn * NCK;  // 1024

DEV float b2f(u16 s) { union { float f; u32 u; } x; x.u = ((u32)s) << 16; return x.f; }
DEV u16 f2b(float f) {
  union { float f; u32 u; } x; x.f = f; u32 u = x.u;
  return (u16)((u + 0x7fffu + ((u >> 16) & 1u)) >> 16);  // RNE
}

DEV void cp16(const void* g, void* l) {
  __builtin_amdgcn_global_load_lds(
      (const __attribute__((address_space(1))) u32*)(unsigned long long)(g),
      (__attribute__((address_space(3))) u32*)(unsigned long long)(l), 16, 0, 0);
}

DEV f32x4 mfma16(short8 a, short8 b, f32x4 c) {
  return __builtin_amdgcn_mfma_f32_16x16x32_bf16(a, b, c, 0, 0, 0);
}

DEV short8 scale8(short8 v, float sc) {
  short8 o;
#pragma unroll
  for (int e = 0; e < 8; e++) o[e] = (short)f2b(b2f((u16)v[e]) * sc);
  return o;
}

// ---------------- fp32 -> bf16 elementwise convert ----------------
__global__ void k_cvt(const float* __restrict__ src, u16* __restrict__ dst, int n8) {
  int i = blockIdx.x * blockDim.x + threadIdx.x;
  if (i >= n8) return;
  const float4* s4 = (const float4*)(src + (size_t)i * 8);
  float4 a = s4[0], b = s4[1];
  u16 o[8] = {f2b(a.x), f2b(a.y), f2b(a.z), f2b(a.w), f2b(b.x), f2b(b.y), f2b(b.z), f2b(b.w)};
  *(short8*)(dst + (size_t)i * 8) = *(short8*)o;
}

// ---------------- vectorized 2048^2 transpose + downcast (float4 in, short8 out) --
struct Trans2Args { const float* src[4]; u16* dst[4]; };
__global__ __launch_bounds__(256) void k_trans2(Trans2Args t) {
  __shared__ u16 tile[64][72];
  const float* src = t.src[blockIdx.z];
  u16* dst = t.dst[blockIdx.z];
  int r0 = blockIdx.y * 64, c0 = blockIdx.x * 64;
  int tid = threadIdx.x;
  int lr = tid >> 2, lc = (tid & 3) * 16;
  const float* s = src + (size_t)(r0 + lr) * 2048 + c0 + lc;
#pragma unroll
  for (int i = 0; i < 4; i++) {
    float4 v = *(const float4*)(s + i * 4);
    tile[lr][lc + i * 4 + 0] = f2b(v.x);
    tile[lr][lc + i * 4 + 1] = f2b(v.y);
    tile[lr][lc + i * 4 + 2] = f2b(v.z);
    tile[lr][lc + i * 4 + 3] = f2b(v.w);
  }
  __syncthreads();
  int orr = tid >> 2, oc = (tid & 3) * 16;
  u16* d = dst + (size_t)(c0 + orr) * 2048 + r0 + oc;
  u16 buf[16];
#pragma unroll
  for (int e = 0; e < 16; e++) buf[e] = tile[oc + e][orr];
  *(short8*)(d) = *(short8*)buf;
  *(short8*)(d + 8) = *(short8*)(buf + 8);
}

// ---------------- small transpose (Wb 2048x16) ----------------
struct TransArgs {
  const float* src[1]; u16* dst[1]; int rows[1]; int cols[1];
};
__global__ void k_trans(TransArgs t) {
  __shared__ u16 tile[32][33];
  const float* src = t.src[0]; u16* dst = t.dst[0];
  int rows = t.rows[0], cols = t.cols[0];
  int r0 = blockIdx.y * 32, c0 = blockIdx.x * 32;
  if (r0 >= rows || c0 >= cols) return;
  int tx = threadIdx.x, ty = threadIdx.y;
  for (int i = ty; i < 32; i += 8) {
    int r = r0 + i, c = c0 + tx;
    if (r < rows && c < cols) tile[i][tx] = f2b(src[(size_t)r * cols + c]);
  }
  __syncthreads();
  for (int i = ty; i < 32; i += 8) {
    int r = c0 + i, c = r0 + tx;
    if (r < cols && c < rows) dst[(size_t)r * rows + c] = tile[tx][i];
  }
}

// ---------------- beta = sigmoid(hs @ Wb), K-split MFMA GEMV ----------------
__global__ __launch_bounds__(256) void k_beta(const u16* __restrict__ hs,
                                              const u16* __restrict__ WbT,
                                              float* __restrict__ beta_g) {
  __shared__ float part[256];  // [head][tokr]
  int tid = threadIdx.x, wave = tid >> 6, lane = tid & 63, quad = lane >> 4, l15 = lane & 15;
  int tok0 = blockIdx.x * 16;
  const u16* arow = hs + (size_t)(tok0 + l15) * Dn + wave * 512;   // A[m=l15][k-slice]
  const u16* brow = WbT + (size_t)l15 * Dn + wave * 512;           // B[n=head=l15][k-slice]
  f32x4 acc = {0.f, 0.f, 0.f, 0.f};
#pragma unroll
  for (int k = 0; k < 512; k += 32) {
    short8 af = *(const short8*)&arow[k + quad * 8];
    short8 bf = *(const short8*)&brow[k + quad * 8];
    acc = mfma16(af, bf, acc);
  }
  part[tid] = 0.f;
  __syncthreads();
#pragma unroll
  for (int r = 0; r < 4; r++) atomicAdd(&part[l15 * 16 + quad * 4 + r], acc[r]);
  __syncthreads();
  int h = tid >> 4, tr = tid & 15;
  int b = tok0 >> 11;
  int l = (tok0 + tr) & 2047;
  beta_g[(size_t)(b * Hn + h) * Ln + l] = 1.f / (1.f + __expf(-part[h * 16 + tr]));
}

// ---------------- fused QKV GEMM: 256x256 tile, 8-phase pipeline (m201 template) --
// A [4096][2048], Bt [6144][2048] (WqT|WkT|WvT), C = qn base; block's 256 cols lie
// entirely in one z (256 | 2048) -> z = bx>>3; silu on z==2.
// Geometry: 512 thr (8 waves, 2M x 4N), per-wave C = 128x64, acc[8][4].
// LDS 128KiB: A/B x 2dbuf x 2half(128x64). One half-tile staged per phase:
//   window T: P0:(T+1).Ah0  P1:(T+1).Ah1  (into idle dbuf)
//             P2:(T+2).Bh0  P3:(T+2).Bh1  (into current dbuf after B-reads close)
// Counted vmcnt(4) ONCE per window, placed BEFORE the window's final barrier so
// every wave's stage-loads are gated before any wave crosses into the next
// window's ds_reads (cross-wave hazard). vmcnt(0) only at window NT-2 (drain).
// Swizzle: phys 16B-slot = logical ^ (row&7); source pre-swizzled, read XOR'd ->
// 2 lanes/bank-group per quarter-wave = conflict-free (both-sides rule #21).
struct Gemm3Args { const u16* A; const u16* Bt; u16* C; int K; };

__global__ __launch_bounds__(512, 1) void k_gemm3(Gemm3Args g) {
  __shared__ u16 sh3[65536];  // 131072B: A slots (d*2+h)*8192 u16; B at +32768 u16
  const int NT = g.K / 64;
  const size_t Kb = (size_t)g.K * 2;
  int tid = threadIdx.x, wave = tid >> 6, lane = tid & 63;
  int quad = lane >> 4, l15 = lane & 15;
  int wm = wave >> 2, wn = wave & 3;

  // bijective XCD swizzle: 384 % 8 == 0, 48 contiguous tiles per XCD
  int bid = blockIdx.x;
  int wg = (bid & 7) * 48 + (bid >> 3);
  int by = wg / 24, bx = wg - by * 24;
  int m0 = by * 256, n0 = bx * 256;

  // stage source col pre-swizzle: lane covers phys slot (lane&7) of row (lane>>3)
  int scb = ((lane & 7) ^ (lane >> 3)) * 16;
  const char* gA = (const char*)g.A + (size_t)(m0 + wave * 16 + (lane >> 3)) * Kb + scb;
  const char* gB = (const char*)g.Bt + (size_t)(n0 + wave * 16 + (lane >> 3)) * Kb + scb;
  u16* dst0 = &sh3[wave * 1024 + lane * 8];

  auto stA = [&](int d, int h, int t) {
    const char* src = gA + (size_t)(h * 128) * Kb + (size_t)t * 128;
    u16* dp = dst0 + (d * 2 + h) * 8192;
    cp16(src, dp);
    cp16(src + (size_t)8 * Kb, dp + 512);
  };
  auto stB = [&](int d, int h, int t) {
    const char* src = gB + (size_t)(h * 128) * Kb + (size_t)t * 128;
    u16* dp = dst0 + 32768 + (d * 2 + h) * 8192;
    cp16(src, dp);
    cp16(src + (size_t)8 * Kb, dp + 512);
  };

  f32x4 acc[8][4];
#pragma unroll
  for (int i = 0; i < 8; i++)
#pragma unroll
    for (int j = 0; j < 4; j++) acc[i][j] = (f32x4){0.f, 0.f, 0.f, 0.f};
  short8 av[4][2], b0[2][2], b1[2][2];

  int cbk0 = (quad ^ (l15 & 7)) * 16;         // kk=0 phys col-bytes; kk=1 = ^64
  int aro = l15 * 128;
  int bro = ((wn & 1) * 64 + l15) * 128;

  // prologue: tile0 all 4 halves (dbuf0) + tile1 B halves (dbuf1); gate + barrier
  stB(0, 0, 0); stB(0, 1, 0);
  stA(0, 0, 0); stA(0, 1, 0);
  stB(1, 0, 1); stB(1, 1, 1);
  asm volatile("s_waitcnt vmcnt(4)" ::: "memory");  // tile0 landed; t1.B in flight
  __builtin_amdgcn_s_barrier();

  for (int T = 0; T < NT; ++T) {
    int d = T & 1, dn = d ^ 1;
    const char* aBs = (const char*)sh3 + (d * 2 + wm) * 16384;
    const char* bBs = (const char*)sh3 + 65536 + (d * 2 + (wn >> 1)) * 16384;
    bool pfA = (T + 1 < NT), pfB = (T + 2 < NT);

    // ---- P0 (mh0,nh0): read A0(8)+B0(4); stage (T+1).Ah0 ----
#pragma unroll
    for (int ii = 0; ii < 4; ii++) {
      av[ii][0] = *(const short8*)(aBs + aro + ii * 2048 + cbk0);
      av[ii][1] = *(const short8*)(aBs + aro + ii * 2048 + (cbk0 ^ 64));
    }
#pragma unroll
    for (int jj = 0; jj < 2; jj++) {
      b0[jj][0] = *(const short8*)(bBs + bro + jj * 2048 + cbk0);
      b0[jj][1] = *(const short8*)(bBs + bro + jj * 2048 + (cbk0 ^ 64));
    }
    if (pfA) stA(dn, 0, T + 1);
    __builtin_amdgcn_s_barrier();
    asm volatile("s_waitcnt lgkmcnt(0)" ::: "memory");
    __builtin_amdgcn_sched_barrier(0);
    __builtin_amdgcn_s_setprio(1);
#pragma unroll
    for (int ii = 0; ii < 4; ii++)
#pragma unroll
      for (int jj = 0; jj < 2; jj++) {
        acc[ii][jj] = mfma16(av[ii][0], b0[jj][0], acc[ii][jj]);
        acc[ii][jj] = mfma16(av[ii][1], b0[jj][1], acc[ii][jj]);
      }
    __builtin_amdgcn_s_setprio(0);
    __builtin_amdgcn_s_barrier();

    // ---- P1 (mh0,nh1): read B1(4); stage (T+1).Ah1 ----
#pragma unroll
    for (int jj = 0; jj < 2; jj++) {
      b1[jj][0] = *(const short8*)(bBs + bro + 4096 + jj * 2048 + cbk0);
      b1[jj][1] = *(const short8*)(bBs + bro + 4096 + jj * 2048 + (cbk0 ^ 64));
    }
    if (pfA) stA(dn, 1, T + 1);
    __builtin_amdgcn_s_barrier();
    asm volatile("s_waitcnt lgkmcnt(0)" ::: "memory");
    __builtin_amdgcn_sched_barrier(0);
    __builtin_amdgcn_s_setprio(1);
#pragma unroll
    for (int ii = 0; ii < 4; ii++)
#pragma unroll
      for (int jj = 0; jj < 2; jj++) {
        acc[ii][2 + jj] = mfma16(av[ii][0], b1[jj][0], acc[ii][2 + jj]);
        acc[ii][2 + jj] = mfma16(av[ii][1], b1[jj][1], acc[ii][2 + jj]);
      }
    __builtin_amdgcn_s_setprio(0);
    __builtin_amdgcn_s_barrier();

    // ---- P2 (mh1,nh1): read A1(8); stage (T+2).Bh0 (B(d) reads closed at P1) ----
#pragma unroll
    for (int ii = 0; ii < 4; ii++) {
      av[ii][0] = *(const short8*)(aBs + 8192 + aro + ii * 2048 + cbk0);
      av[ii][1] = *(const short8*)(aBs + 8192 + aro + ii * 2048 + (cbk0 ^ 64));
    }
    if (pfB) stB(d, 0, T + 2);
    __builtin_amdgcn_s_barrier();
    asm volatile("s_waitcnt lgkmcnt(0)" ::: "memory");
    __builtin_amdgcn_sched_barrier(0);
    __builtin_amdgcn_s_setprio(1);
#pragma unroll
    for (int ii = 0; ii < 4; ii++)
#pragma unroll
      for (int jj = 0; jj < 2; jj++) {
        acc[4 + ii][2 + jj] = mfma16(av[ii][0], b1[jj][0], acc[4 + ii][2 + jj]);
        acc[4 + ii][2 + jj] = mfma16(av[ii][1], b1[jj][1], acc[4 + ii][2 + jj]);
      }
    __builtin_amdgcn_s_setprio(0);
    __builtin_amdgcn_s_barrier();

    // ---- P3 (mh1,nh0): no reads; stage (T+2).Bh1; window-exit vmcnt gate ----
    if (pfB) stB(d, 1, T + 2);
    __builtin_amdgcn_s_setprio(1);
#pragma unroll
    for (int ii = 0; ii < 4; ii++)
#pragma unroll
      for (int jj = 0; jj < 2; jj++) {
        acc[4 + ii][jj] = mfma16(av[ii][0], b0[jj][0], acc[4 + ii][jj]);
        acc[4 + ii][jj] = mfma16(av[ii][1], b0[jj][1], acc[4 + ii][jj]);
      }
    __builtin_amdgcn_s_setprio(0);
    if (T == NT - 2) asm volatile("s_waitcnt vmcnt(0)" ::: "memory");
    else if (T < NT - 2) asm volatile("s_waitcnt vmcnt(4)" ::: "memory");
    __builtin_amdgcn_s_barrier();
  }

  // epilogue: whole block in one z (256-aligned boundary)
  int z = n0 >> 11;
  u16* Cz = g.C + (size_t)z * ((size_t)Mrows * 2048);
  int colb = (n0 & 2047) + wn * 64;
  int rowb = m0 + wm * 128;
#pragma unroll
  for (int i = 0; i < 8; i++)
#pragma unroll
    for (int j = 0; j < 4; j++) {
      int row = rowb + i * 16 + quad * 4;
      int col = colb + j * 16 + l15;
#pragma unroll
      for (int r = 0; r < 4; r++) {
        float v = acc[i][j][r];
        if (z == 2) v = v / (1.f + __expf(-v));  // silu (v-projection)
        Cz[(size_t)(row + r) * 2048 + col] = f2b(v);
      }
    }
}

// ---------------- Wo GEMM: 128x256 tile, 4-phase unit pipeline, f32 out ----------
// Verified r8 template port (grid 256 = 1/CU, vmcnt(3) counted, swizzle pair).
struct GemmoArgs { const u16* A; const u16* Bt; float* C; int K; };

__global__ __launch_bounds__(512, 2) void k_gemmo(GemmoArgs g) {
  // A slots: 3 x 8192B at 0; B slots: 3 x 16384B at 24576. Total 73728B.
  __shared__ u16 ldsbuf[36864];
  const char* LB = (const char*)ldsbuf;
  const int K = g.K, NT = K / 64;
  const size_t Kb = (size_t)K * 2;
  int tid = threadIdx.x, wave = tid >> 6, lane = tid & 63;
  int quad = lane >> 4, l15 = lane & 15;
  int wm = wave >> 2, wn = wave & 3;  // 2M x 4N; per-wave C = 64x64

  // XCD swizzle: chunk = one bx column (B-panel 2MB L2-resident per XCD)
  int bid = blockIdx.x;
  int wg = (bid & 7) * 32 + (bid >> 3);
  int bx = wg >> 5, by = wg & 31;
  int m0 = by * 128, n0 = bx * 256;

  int r0 = tid >> 2;
  int cby = (((tid & 3) ^ ((tid >> 3) & 3)) * 16);
  const char* gA = (const char*)g.A + (size_t)(m0 + r0) * Kb + cby;
  const char* gB = (const char*)g.Bt + (size_t)(n0 + r0) * Kb + cby;

  auto stageA = [&](int slot, int t, int kh) {
    const char* src = gA + (size_t)t * 128 + kh * 64;
    cp16(src, &ldsbuf[slot * 4096 + tid * 8]);
  };
  auto stageB = [&](int slot, int t, int kh) {
    const char* src = gB + (size_t)t * 128 + kh * 64;
    u16* dst = &ldsbuf[12288 + slot * 8192 + tid * 8];
    cp16(src, dst);
    cp16(src + (size_t)128 * Kb, dst + 4096);
  };

  f32x4 acc[4][4];
#pragma unroll
  for (int i = 0; i < 4; i++)
#pragma unroll
    for (int j = 0; j < 4; j++) acc[i][j] = (f32x4){0.f, 0.f, 0.f, 0.f};

  int rsw = (l15 >> 1) & 3;
  int rA = (wm * 64 + l15) * 64 + ((quad ^ rsw) * 16);  // + i*1024
  int rB = (wn * 64 + l15) * 64 + ((quad ^ rsw) * 16);  // + (jh*2+j)*1024

  stageA(0, 0, 0);
  stageB(0, 0, 0);
  stageA(1, 0, 1);
  stageB(1, 0, 1);

  short8 av[4];
  int u0 = 0;
  for (int t = 0; t < NT; ++t) {
    int u1 = u0 + 1; if (u1 == 3) u1 = 0;
    int u2 = u1 + 1; if (u2 == 3) u2 = 0;
    bool pf = (t + 1 < NT);
    const char* aK0 = LB + u0 * 8192;
    const char* aK1 = LB + u1 * 8192;
    const char* bK0 = LB + 24576 + u0 * 16384;
    const char* bK1 = LB + 24576 + u1 * 16384;

    // ---- phase 0: (kh0, jh0); stage A(t+1,0) -> u2 ----
    asm volatile("s_waitcnt vmcnt(3)" ::: "memory");
    __builtin_amdgcn_s_barrier();
    __builtin_amdgcn_sched_barrier(0);
    if (pf) stageA(u2, t + 1, 0);
    {
      short8 bv[2];
#pragma unroll
      for (int i = 0; i < 4; i++) av[i] = *(const short8*)(aK0 + rA + i * 1024);
#pragma unroll
      for (int j = 0; j < 2; j++) bv[j] = *(const short8*)(bK0 + rB + j * 1024);
      __builtin_amdgcn_s_setprio(1);
#pragma unroll
      for (int i = 0; i < 4; i++)
#pragma unroll
        for (int j = 0; j < 2; j++) acc[i][j] = mfma16(av[i], bv[j], acc[i][j]);
      __builtin_amdgcn_s_setprio(0);
    }

    // ---- phase 1: (kh0, jh1); stage B(t+1,0) -> u2 ----
    asm volatile("s_waitcnt vmcnt(3)" ::: "memory");
    __builtin_amdgcn_s_barrier();
    __builtin_amdgcn_sched_barrier(0);
    if (pf) stageB(u2, t + 1, 0);
    {
      short8 bv[2];
#pragma unroll
      for (int j = 0; j < 2; j++) bv[j] = *(const short8*)(bK0 + rB + (2 + j) * 1024);
      __builtin_amdgcn_s_setprio(1);
#pragma unroll
      for (int i = 0; i < 4; i++)
#pragma unroll
        for (int j = 0; j < 2; j++) acc[i][2 + j] = mfma16(av[i], bv[j], acc[i][2 + j]);
      __builtin_amdgcn_s_setprio(0);
    }

    // ---- phase 2: (kh1, jh0); stage A(t+1,1) -> u0 ----
    if (t == NT - 1) asm volatile("s_waitcnt vmcnt(0)" ::: "memory");
    else asm volatile("s_waitcnt vmcnt(3)" ::: "memory");
    __builtin_amdgcn_s_barrier();
    __builtin_amdgcn_sched_barrier(0);
    if (pf) stageA(u0, t + 1, 1);
    {
      short8 bv[2];
#pragma unroll
      for (int i = 0; i < 4; i++) av[i] = *(const short8*)(aK1 + rA + i * 1024);
#pragma unroll
      for (int j = 0; j < 2; j++) bv[j] = *(const short8*)(bK1 + rB + j * 1024);
      __builtin_amdgcn_s_setprio(1);
#pragma unroll
      for (int i = 0; i < 4; i++)
#pragma unroll
        for (int j = 0; j < 2; j++) acc[i][j] = mfma16(av[i], bv[j], acc[i][j]);
      __builtin_amdgcn_s_setprio(0);
    }

    // ---- phase 3: (kh1, jh1); stage B(t+1,1) -> u0 ----
    asm volatile("s_waitcnt vmcnt(3)" ::: "memory");
    __builtin_amdgcn_s_barrier();
    __builtin_amdgcn_sched_barrier(0);
    if (pf) stageB(u0, t + 1, 1);
    {
      short8 bv[2];
#pragma unroll
      for (int j = 0; j < 2; j++) bv[j] = *(const short8*)(bK1 + rB + (2 + j) * 1024);
      __builtin_amdgcn_s_setprio(1);
#pragma unroll
      for (int i = 0; i < 4; i++)
#pragma unroll
        for (int j = 0; j < 2; j++) acc[i][2 + j] = mfma16(av[i], bv[j], acc[i][2 + j]);
      __builtin_amdgcn_s_setprio(0);
    }

    u0 = u2;
  }

  // epilogue: f32 out
#pragma unroll
  for (int i = 0; i < 4; i++)
#pragma unroll
    for (int j = 0; j < 4; j++) {
      int row = m0 + wm * 64 + i * 16 + quad * 4;
      int col = n0 + wn * 64 + j * 16 + l15;
#pragma unroll
      for (int r = 0; r < 4; r++)
        g.C[(size_t)(row + r) * 2048 + col] = acc[i][j][r];
    }
}

// ---------------- per-chunk precompute + FUSED l2-norm ----------------
constexpr int ST = 72;
__global__ __launch_bounds__(256, 4) void k_pre(
    const float* __restrict__ beta_g,
    const u16* __restrict__ qn, const u16* __restrict__ kn, const u16* __restrict__ vn,
    u16* __restrict__ W2g, u16* __restrict__ Ug, u16* __restrict__ Gg, u16* __restrict__ KTg,
    u16* __restrict__ Qg) {
  __shared__ float beta_s[64];
  __shared__ float rnk_s[64], rnq_s[64];
  __shared__ u16 mats[4 * 64 * ST];
  int gid = blockIdx.x;
  int c = gid & 31, h = (gid >> 5) & 15, b = gid >> 9;
  int tid = threadIdx.x;
  int l0 = c * 64;

  int wave = tid >> 6, lane = tid & 63, quad = lane >> 4, l15 = lane & 15;
  u16 *Br = mats, *Bc = mats + 64 * ST, *M0 = mats + 2 * 64 * ST, *M1 = mats + 3 * 64 * ST;

  // row norms for this block's 64 tokens (rows wave*16+l15, 4-lane spread)
  short8 bfr[4], qfr[4];
  {
    int row = wave * 16 + l15;
    const u16* krow = kn + (size_t)(b * Ln + l0 + row) * Dn + h * 128;
    const u16* qrow = qn + (size_t)(b * Ln + l0 + row) * Dn + h * 128;
    float ssk = 0.f, ssq = 0.f;
#pragma unroll
    for (int s = 0; s < 4; s++) {
      bfr[s] = *(const short8*)&krow[quad * 8 + 32 * s];
      qfr[s] = *(const short8*)&qrow[quad * 8 + 32 * s];
#pragma unroll
      for (int e = 0; e < 8; e++) {
        float xk = b2f((u16)bfr[s][e]), xq = b2f((u16)qfr[s][e]);
        ssk += xk * xk; ssq += xq * xq;
      }
    }
    ssk += __shfl_xor(ssk, 16, 64); ssk += __shfl_xor(ssk, 32, 64);
    ssq += __shfl_xor(ssq, 16, 64); ssq += __shfl_xor(ssq, 32, 64);
    float rk = 1.f / fmaxf(sqrtf(ssk), 1e-12f);
    float rq = 0.08838834764831845f / fmaxf(sqrtf(ssq), 1e-12f);  // dh^-0.5 folded
    if (quad == 0) { rnk_s[row] = rk; rnq_s[row] = rq; }
#pragma unroll
    for (int s = 0; s < 4; s++) {
      bfr[s] = scale8(bfr[s], rk);
      *(short8*)&Qg[(size_t)gid * 8192 + (size_t)row * 128 + quad * 8 + 32 * s] =
          scale8(qfr[s], rq);
    }
  }
  if (tid < 64) beta_s[tid] = beta_g[(size_t)(b * Hn + h) * Ln + l0 + tid];
  __syncthreads();

  // P1: A_full = Kn Kn^T, G = tril(Qn Kn^T); B=-strict_tril(diag(beta)A), M=I+B
  {
#pragma unroll
    for (int mt = 0; mt < 4; ++mt) {
      const u16* arow_k = kn + (size_t)(b * Ln + l0 + mt * 16 + l15) * Dn + h * 128;
      const u16* arow_q = qn + (size_t)(b * Ln + l0 + mt * 16 + l15) * Dn + h * 128;
      float rkA = rnk_s[mt * 16 + l15], rqA = rnq_s[mt * 16 + l15];
      f32x4 accA = {0.f, 0.f, 0.f, 0.f}, accG = {0.f, 0.f, 0.f, 0.f};
#pragma unroll
      for (int s = 0; s < 4; s++) {
        short8 ak = scale8(*(const short8*)&arow_k[quad * 8 + 32 * s], rkA);
        short8 aq = scale8(*(const short8*)&arow_q[quad * 8 + 32 * s], rqA);
        accA = mfma16(ak, bfr[s], accA);
        accG = mfma16(aq, bfr[s], accG);
      }
      int t = wave * 16 + l15;
#pragma unroll
      for (int r = 0; r < 4; r++) {
        int i = mt * 16 + quad * 4 + r;
        u16 nb = f2b((t < i) ? -beta_s[i] * accA[r] : 0.f);
        Br[i * ST + t] = nb;
        Bc[t * ST + i] = nb;
        M0[i * ST + t] = (t == i) ? f2b(1.f) : nb;
        Gg[(size_t)gid * 4096 + (size_t)i * 64 + t] = f2b((t <= i) ? accG[r] : 0.f);
      }
    }
  }
  __syncthreads();

  // P2: Minv = (I+B)(I+B^2)(I+B^4)(I+B^8)(I+B^16)(I+B^32)
  u16 *Mc = M0, *Mn = M1;
#pragma unroll
  for (int it = 0; it < 5; ++it) {
    const int tT = (it < 3) ? 0 : ((it == 3) ? 1 : 2);
    const int tI = (it < 4) ? 0 : 1;
    short8 bb[2];
#pragma unroll
    for (int s = 0; s < 2; s++) bb[s] = *(const short8*)&Bc[(wave * 16 + l15) * ST + quad * 8 + 32 * s];
    f32x4 accT[4];
#pragma unroll
    for (int mt = 0; mt < 4; mt++) {
      accT[mt] = (f32x4){0.f, 0.f, 0.f, 0.f};
      if (mt - wave >= tT) {
#pragma unroll
        for (int s = 0; s < 2; s++) {
          short8 af = *(const short8*)&Br[(mt * 16 + l15) * ST + quad * 8 + 32 * s];
          accT[mt] = mfma16(af, bb[s], accT[mt]);
        }
      }
    }
    __syncthreads();  // all lanes done reading Br/Bc -> safe to overwrite
#pragma unroll
    for (int mt = 0; mt < 4; mt++) {
      if (mt - wave >= tI) {
#pragma unroll
        for (int r = 0; r < 4; r++) {
          int i = mt * 16 + quad * 4 + r, t = wave * 16 + l15;
          u16 v = f2b(accT[mt][r]);
          Br[i * ST + t] = v;
          Bc[t * ST + i] = v;
        }
      }
    }
    __syncthreads();  // T visible
    short8 tb[2];
#pragma unroll
    for (int s = 0; s < 2; s++) tb[s] = *(const short8*)&Bc[(wave * 16 + l15) * ST + quad * 8 + 32 * s];
#pragma unroll
    for (int mt = 0; mt < 4; mt++) {
      if (mt - wave >= tT) {
        f32x4 a;
#pragma unroll
        for (int r = 0; r < 4; r++) a[r] = b2f(Mc[(mt * 16 + quad * 4 + r) * ST + wave * 16 + l15]);
#pragma unroll
        for (int s = 0; s < 2; s++) {
          short8 af = *(const short8*)&Mc[(mt * 16 + l15) * ST + quad * 8 + 32 * s];
          a = mfma16(af, tb[s], a);
        }
#pragma unroll
        for (int r = 0; r < 4; r++) Mn[(mt * 16 + quad * 4 + r) * ST + wave * 16 + l15] = f2b(a[r]);
      } else {
#pragma unroll
        for (int r = 0; r < 4; r++)
          Mn[(mt * 16 + quad * 4 + r) * ST + wave * 16 + l15] =
              Mc[(mt * 16 + quad * 4 + r) * ST + wave * 16 + l15];
      }
    }
    u16* tmp = Mc; Mc = Mn; Mn = tmp;
  }
  __syncthreads();  // drain last M-update before P3 reuses slots

  // P3 (vectorized): Mb = Minv*diag(beta); XT = normalized K^T (pass0) / raw V^T
  // (pass1); KTg coalesced copy of normalized K^T.
  u16* XT = mats;
  u16* Mb = Mn;  // free slot after odd number of swaps
  for (int idx = tid; idx < 512; idx += 256) {
    int i = idx >> 3, t8 = (idx & 7) * 8;
    short8 m8 = *(const short8*)&Mc[i * ST + t8];
    short8 o8;
#pragma unroll
    for (int e = 0; e < 8; e++) o8[e] = (short)f2b(b2f((u16)m8[e]) * beta_s[t8 + e]);
    *(short8*)&Mb[i * ST + t8] = o8;
  }
  int tv = tid & 63, dk0 = (tid >> 6) * 32;  // lane->token row, wave->dk block
  for (int pass = 0; pass < 2; ++pass) {
    const u16* src = pass ? vn : kn;
    const u16* srow = src + (size_t)(b * Ln + l0 + tv) * Dn + h * 128 + dk0;
    float rsc = pass ? 1.f : rnk_s[tv];
#pragma unroll
    for (int s = 0; s < 4; s++) {
      short8 vv = *(const short8*)&srow[s * 8];
      if (!pass) vv = scale8(vv, rsc);
#pragma unroll
      for (int e = 0; e < 8; e++) XT[(dk0 + s * 8 + e) * ST + tv] = (u16)vv[e];
    }
    __syncthreads();
    if (pass == 0) {
#pragma unroll
      for (int it2 = 0; it2 < 4; it2++) {
        int idx = tid + it2 * 256;
        int dk = idx >> 3, t0 = (idx & 7) * 8;
        *(short8*)&KTg[(size_t)gid * 8192 + dk * 64 + t0] =
            *(const short8*)&XT[dk * ST + t0];
      }
    }
    u16* dst = pass ? Ug : W2g;
#pragma unroll
    for (int half = 0; half < 2; ++half) {
      int nt = wave + half * 4;
      short8 bx[2];
#pragma unroll
      for (int s = 0; s < 2; s++) bx[s] = *(const short8*)&XT[(nt * 16 + l15) * ST + quad * 8 + 32 * s];
#pragma unroll
      for (int mt = 0; mt < 4; mt++) {
        f32x4 a = {0.f, 0.f, 0.f, 0.f};
#pragma unroll
        for (int s = 0; s < 2; s++) {
          short8 af = *(const short8*)&Mb[(mt * 16 + l15) * ST + quad * 8 + 32 * s];
          a = mfma16(af, bx[s], a);
        }
#pragma unroll
        for (int r = 0; r < 4; r++)
          dst[(size_t)gid * 8192 + (size_t)(mt * 16 + quad * 4 + r) * 128 + nt * 16 + l15] = f2b(a[r]);
      }
    }
    __syncthreads();
  }
}

// ---------------- sequential chunk scan (per b,h and 16-wide v-slice) ----------------
struct Frg { short8 w2[4], qf[4], gf[2], k0[2], k1[2]; float u[4]; };

__global__ __launch_bounds__(256) void k_scan(
    const u16* __restrict__ Qg, const u16* __restrict__ W2g, const u16* __restrict__ Ug,
    const u16* __restrict__ Gg, const u16* __restrict__ KTg, u16* __restrict__ Og) {
  constexpr int SST = 136, DST = 104;
  __shared__ u16 Sb[16 * SST];  // S^T slice, bf16 shadow: [v][dk]
  __shared__ u16 Db[16 * DST];  // Delta^T slice: [v][t]
  int bh = blockIdx.x, sl = blockIdx.y;
  int b = bh >> 4, h = bh & 15, c0 = sl * 16;
  int tid = threadIdx.x, wave = tid >> 6, lane = tid & 63, quad = lane >> 4, l15 = lane & 15;
  for (int i = tid; i < 16 * SST; i += 256) Sb[i] = 0;
  f32x4 accS0 = {0.f, 0.f, 0.f, 0.f}, accS1 = {0.f, 0.f, 0.f, 0.f};  // fp32 master state
  __syncthreads();

  auto load_frags = [&](Frg& F, int ci) {
    size_t ck = (size_t)bh * NCK + ci;
    const u16* w2row = W2g + ck * 8192 + (size_t)(wave * 16 + l15) * 128;
    const u16* qrow = Qg + ck * 8192 + (size_t)(wave * 16 + l15) * 128;
#pragma unroll
    for (int s = 0; s < 4; s++) {
      F.w2[s] = *(const short8*)&w2row[quad * 8 + 32 * s];
      F.qf[s] = *(const short8*)&qrow[quad * 8 + 32 * s];
    }
    const u16* grow = Gg + ck * 4096 + (size_t)(wave * 16 + l15) * 64;
    const u16* kt0 = KTg + ck * 8192 + (size_t)(wave * 16 + l15) * 64;
    const u16* kt1 = KTg + ck * 8192 + (size_t)((wave + 4) * 16 + l15) * 64;
#pragma unroll
    for (int s = 0; s < 2; s++) {
      F.gf[s] = *(const short8*)&grow[quad * 8 + 32 * s];
      F.k0[s] = *(const short8*)&kt0[quad * 8 + 32 * s];
      F.k1[s] = *(const short8*)&kt1[quad * 8 + 32 * s];
    }
    const u16* urow = Ug + ck * 8192 + (size_t)(wave * 16 + quad * 4) * 128 + c0 + l15;
#pragma unroll
    for (int r = 0; r < 4; r++) F.u[r] = b2f(urow[(size_t)r * 128]);
  };

  auto compute = [&](const Frg& F, int ci) {
    f32x4 accT = {0.f, 0.f, 0.f, 0.f}, accO = {0.f, 0.f, 0.f, 0.f};
#pragma unroll
    for (int s = 0; s < 4; s++) {
      short8 sf = *(const short8*)&Sb[l15 * SST + quad * 8 + 32 * s];
      accT = mfma16(F.w2[s], sf, accT);   // W2 @ S0
      accO = mfma16(F.qf[s], sf, accO);   // Q @ S0
    }
#pragma unroll
    for (int r = 0; r < 4; r++) {
      float d = F.u[r] - accT[r];         // Delta = U - W2@S0
      Db[l15 * DST + wave * 16 + quad * 4 + r] = f2b(d);
    }
    __syncthreads();
#pragma unroll
    for (int s = 0; s < 2; s++) {
      short8 df = *(const short8*)&Db[l15 * DST + quad * 8 + 32 * s];
      accO = mfma16(F.gf[s], df, accO);   // O += tril(QK^T) @ Delta
      accS0 = mfma16(F.k0[s], df, accS0); // S += K^T @ Delta
      accS1 = mfma16(F.k1[s], df, accS1);
    }
    u16* orow = Og + (size_t)(b * Ln + ci * 64 + wave * 16 + quad * 4) * Dn + h * 128 + c0 + l15;
#pragma unroll
    for (int r = 0; r < 4; r++) orow[(size_t)r * Dn] = f2b(accO[r]);
#pragma unroll
    for (int r = 0; r < 4; r++) {
      Sb[l15 * SST + wave * 16 + quad * 4 + r] = f2b(accS0[r]);
      Sb[l15 * SST + (wave + 4) * 16 + quad * 4 + r] = f2b(accS1[r]);
    }
    __syncthreads();
  };

  Frg FA, FB;
  load_frags(FA, 0);
  for (int ci = 0; ci < NCK; ci += 2) {
    load_frags(FB, ci + 1);
    compute(FA, ci);
    if (ci + 2 < NCK) load_frags(FA, ci + 2);
    compute(FB, ci + 1);
  }
}

// ---------------- RMSNorm over head dim (fp32 weight) ----------------
__global__ void k_rms(const u16* __restrict__ Og, const float* __restrict__ w, u16* __restrict__ out) {
  int tid = threadIdx.x, wave = tid >> 6, lane = tid & 63;
  size_t row = (size_t)blockIdx.x * 4 + wave;
  const u16* p = Og + row * 128;
  u32 u = *(const u32*)&p[lane * 2];
  float x0 = b2f((u16)(u & 0xffff)), x1 = b2f((u16)(u >> 16));
  float ss = x0 * x0 + x1 * x1;
#pragma unroll
  for (int o = 32; o > 0; o >>= 1) ss += __shfl_xor(ss, o, 64);
  float sc = rsqrtf(ss * (1.f / 128.f) + 1e-5f);
  float w0 = w[lane * 2], w1 = w[lane * 2 + 1];
  u32 o2 = (u32)f2b(x0 * sc * w0) | ((u32)f2b(x1 * sc * w1) << 16);
  *(u32*)&out[row * 128 + lane * 2] = o2;
}

// ---------------- host ----------------
extern "C" void kernel_launch(void* const* d_in, const int* in_sizes, int n_in,
                              void* d_out, int out_size, void* d_ws, size_t ws_size,
                              hipStream_t stream) {
  (void)in_sizes; (void)n_in; (void)out_size; (void)ws_size;
  const float* hs_f = (const float*)d_in[0];
  const float* Wq = (const float*)d_in[1];
  const float* Wk = (const float*)d_in[2];
  const float* Wv = (const float*)d_in[3];
  const float* Wb = (const float*)d_in[4];
  const float* onw = (const float*)d_in[5];
  const float* Wo = (const float*)d_in[6];

  char* ws = (char*)d_ws;
  size_t off = 0;
  auto alloc = [&](size_t bytes) -> void* {
    void* p = ws + off;
    off += (bytes + 255) & ~(size_t)255;
    return p;
  };
  const size_t WB = (size_t)2048 * 2048 * 2;
  const size_t XB = (size_t)4096 * 2048 * 2;
  u16* WqT = (u16*)alloc(WB);   // WqT|WkT|WvT contiguous => fused Bt [6144][2048]
  u16* WkT = (u16*)alloc(WB);
  u16* WvT = (u16*)alloc(WB);
  u16* WoT = (u16*)alloc(WB);
  u16* WbT = (u16*)alloc((size_t)16 * 2048 * 2);
  u16* hsb = (u16*)alloc(XB);
  u16* qn  = (u16*)alloc(XB);   // qn|kn|vn contiguous => fused C
  u16* kn  = (u16*)alloc(XB);
  u16* vn  = (u16*)alloc(XB);   // reused as O after precompute
  u16* W2g = (u16*)alloc((size_t)NCHUNKS * 8192 * 2);
  u16* Ug  = (u16*)alloc((size_t)NCHUNKS * 8192 * 2);
  u16* Gg  = (u16*)alloc((size_t)NCHUNKS * 4096 * 2);
  u16* KTg = (u16*)alloc((size_t)NCHUNKS * 8192 * 2);
  u16* Qg  = (u16*)alloc((size_t)NCHUNKS * 8192 * 2);  // normalized q, chunk layout
  float* beta_g = (float*)alloc((size_t)Bn * Hn * Ln * 4);
  u16* Og = vn;       // v dead after precompute
  u16* onorm = qn;    // q dead after precompute (scan reads Qg)

  // 0) downcast hidden_states
  hipLaunchKernelGGL(k_cvt, dim3(Mrows * Dn / 8 / 256), dim3(256), 0, stream, hs_f, hsb, Mrows * Dn / 8);

  // 1) big weight transposes (vectorized) + Wb (small path)
  Trans2Args t2;
  t2.src[0] = Wq; t2.dst[0] = WqT;
  t2.src[1] = Wk; t2.dst[1] = WkT;
  t2.src[2] = Wv; t2.dst[2] = WvT;
  t2.src[3] = Wo; t2.dst[3] = WoT;
  hipLaunchKernelGGL(k_trans2, dim3(32, 32, 4), dim3(256), 0, stream, t2);
  TransArgs ta;
  ta.src[0] = Wb; ta.dst[0] = WbT; ta.rows[0] = 2048; ta.cols[0] = 16;
  hipLaunchKernelGGL(k_trans, dim3(1, 64, 1), dim3(32, 8), 0, stream, ta);

  // 1b) beta for all heads (K-split, 256 blocks)
  hipLaunchKernelGGL(k_beta, dim3(Mrows / 16), dim3(256), 0, stream, hsb, WbT, beta_g);

  // 2) fused q/k/v projection: 4096x6144x2048 GEMM, 8-phase 256^2 template, grid 384
  {
    Gemm3Args g3;
    g3.A = hsb; g3.Bt = WqT; g3.C = qn; g3.K = 2048;
    hipLaunchKernelGGL(k_gemm3, dim3(384), dim3(512), 0, stream, g3);
  }

  // 3) chunk precompute + fused l2-norm
  hipLaunchKernelGGL(k_pre, dim3(NCHUNKS), dim3(256), 0, stream,
                     beta_g, qn, kn, vn, W2g, Ug, Gg, KTg, Qg);

  // 4) sequential scan (reads normalized q from Qg chunk layout)
  hipLaunchKernelGGL(k_scan, dim3(32, 8), dim3(256), 0, stream,
                     Qg, W2g, Ug, Gg, KTg, Og);

  // 5) RMSNorm
  hipLaunchKernelGGL(k_rms, dim3(16384), dim3(256), 0, stream, Og, onw, onorm);

  // 6) output projection (fp32 out -> d_out), 4-phase 128x256 pipeline, grid 256
  {
    GemmoArgs go;
    go.A = onorm; go.Bt = WoT; go.C = (float*)d_out; go.K = 2048;
    hipLaunchKernelGGL(k_gemmo, dim3(256), dim3(512), 0, stream, go);
  }
}

// Round 11
// 415.024 us; speedup vs baseline: 1.0593x; 1.0593x over previous
//
#include <hip/hip_runtime.h>
#include <hip/hip_bf16.h>
#include <cstdint>

#define DEV static __device__ __forceinline__

typedef unsigned short u16;
typedef unsigned int u32;
typedef __attribute__((ext_vector_type(8))) short short8;
typedef __attribute__((ext_vector_type(4))) float f32x4;

constexpr int Bn = 2, Ln = 2048, Dn = 2048, Hn = 16;
constexpr int Mrows = Bn * Ln;          // 4096
constexpr int CHK = 64, NCK = Ln / CHK; // chunk=64, 32 chunks/seq
constexpr int NCHUNKS = Bn * Hn * NCK;  // 1024

DEV float b2f(u16 s) { union { float f; u32 u; } x; x.u = ((u32)s) << 16; return x.f; }
DEV u16 f2b(float f) {
  union { float f; u32 u; } x; x.f = f; u32 u = x.u;
  return (u16)((u + 0x7fffu + ((u >> 16) & 1u)) >> 16);  // RNE
}

DEV void cp16(const void* g, void* l) {
  __builtin_amdgcn_global_load_lds(
      (const __attribute__((address_space(1))) u32*)(unsigned long long)(g),
      (__attribute__((address_space(3))) u32*)(unsigned long long)(l), 16, 0, 0);
}

DEV f32x4 mfma16(short8 a, short8 b, f32x4 c) {
  return __builtin_amdgcn_mfma_f32_16x16x32_bf16(a, b, c, 0, 0, 0);
}

DEV short8 scale8(short8 v, float sc) {
  short8 o;
#pragma unroll
  for (int e = 0; e < 8; e++) o[e] = (short)f2b(b2f((u16)v[e]) * sc);
  return o;
}

// ---------------- fp32 -> bf16 elementwise convert ----------------
__global__ void k_cvt(const float* __restrict__ src, u16* __restrict__ dst, int n8) {
  int i = blockIdx.x * blockDim.x + threadIdx.x;
  if (i >= n8) return;
  const float4* s4 = (const float4*)(src + (size_t)i * 8);
  float4 a = s4[0], b = s4[1];
  u16 o[8] = {f2b(a.x), f2b(a.y), f2b(a.z), f2b(a.w), f2b(b.x), f2b(b.y), f2b(b.z), f2b(b.w)};
  *(short8*)(dst + (size_t)i * 8) = *(short8*)o;
}

// ---------------- vectorized 2048^2 transpose + downcast (float4 in, short8 out) --
struct Trans2Args { const float* src[4]; u16* dst[4]; };
__global__ __launch_bounds__(256) void k_trans2(Trans2Args t) {
  __shared__ u16 tile[64][72];
  const float* src = t.src[blockIdx.z];
  u16* dst = t.dst[blockIdx.z];
  int r0 = blockIdx.y * 64, c0 = blockIdx.x * 64;
  int tid = threadIdx.x;
  int lr = tid >> 2, lc = (tid & 3) * 16;
  const float* s = src + (size_t)(r0 + lr) * 2048 + c0 + lc;
#pragma unroll
  for (int i = 0; i < 4; i++) {
    float4 v = *(const float4*)(s + i * 4);
    tile[lr][lc + i * 4 + 0] = f2b(v.x);
    tile[lr][lc + i * 4 + 1] = f2b(v.y);
    tile[lr][lc + i * 4 + 2] = f2b(v.z);
    tile[lr][lc + i * 4 + 3] = f2b(v.w);
  }
  __syncthreads();
  int orr = tid >> 2, oc = (tid & 3) * 16;
  u16* d = dst + (size_t)(c0 + orr) * 2048 + r0 + oc;
  u16 buf[16];
#pragma unroll
  for (int e = 0; e < 16; e++) buf[e] = tile[oc + e][orr];
  *(short8*)(d) = *(short8*)buf;
  *(short8*)(d + 8) = *(short8*)(buf + 8);
}

// ---------------- small transpose (Wb 2048x16) ----------------
struct TransArgs {
  const float* src[1]; u16* dst[1]; int rows[1]; int cols[1];
};
__global__ void k_trans(TransArgs t) {
  __shared__ u16 tile[32][33];
  const float* src = t.src[0]; u16* dst = t.dst[0];
  int rows = t.rows[0], cols = t.cols[0];
  int r0 = blockIdx.y * 32, c0 = blockIdx.x * 32;
  if (r0 >= rows || c0 >= cols) return;
  int tx = threadIdx.x, ty = threadIdx.y;
  for (int i = ty; i < 32; i += 8) {
    int r = r0 + i, c = c0 + tx;
    if (r < rows && c < cols) tile[i][tx] = f2b(src[(size_t)r * cols + c]);
  }
  __syncthreads();
  for (int i = ty; i < 32; i += 8) {
    int r = c0 + i, c = r0 + tx;
    if (r < cols && c < rows) dst[(size_t)r * rows + c] = tile[tx][i];
  }
}

// ---------------- beta = sigmoid(hs @ Wb), K-split MFMA GEMV ----------------
__global__ __launch_bounds__(256) void k_beta(const u16* __restrict__ hs,
                                              const u16* __restrict__ WbT,
                                              float* __restrict__ beta_g) {
  __shared__ float part[256];  // [head][tokr]
  int tid = threadIdx.x, wave = tid >> 6, lane = tid & 63, quad = lane >> 4, l15 = lane & 15;
  int tok0 = blockIdx.x * 16;
  const u16* arow = hs + (size_t)(tok0 + l15) * Dn + wave * 512;   // A[m=l15][k-slice]
  const u16* brow = WbT + (size_t)l15 * Dn + wave * 512;           // B[n=head=l15][k-slice]
  f32x4 acc = {0.f, 0.f, 0.f, 0.f};
#pragma unroll
  for (int k = 0; k < 512; k += 32) {
    short8 af = *(const short8*)&arow[k + quad * 8];
    short8 bf = *(const short8*)&brow[k + quad * 8];
    acc = mfma16(af, bf, acc);
  }
  part[tid] = 0.f;
  __syncthreads();
#pragma unroll
  for (int r = 0; r < 4; r++) atomicAdd(&part[l15 * 16 + quad * 4 + r], acc[r]);
  __syncthreads();
  int h = tid >> 4, tr = tid & 15;
  int b = tok0 >> 11;
  int l = (tok0 + tr) & 2047;
  beta_g[(size_t)(b * Hn + h) * Ln + l] = 1.f / (1.f + __expf(-part[h * 16 + tr]));
}

// ---------------- fused QKV GEMM: 256x384 tile, 4-phase unit pipeline ----------------
// VERBATIM round-4 verified structure (121-123 us). FROZEN — r5/r6/r10 all showed
// restructures/ports regress; this is the session's GEMM plateau structure.
struct Gemm2Args { const u16* A; const u16* Bt; u16* C; int K; };

__global__ __launch_bounds__(512, 2) void k_gemm2(Gemm2Args g) {
  // A slots: 3 x 16384B at 0; B slots: 3 x 24576B at 49152. Total 122880B.
  __shared__ u16 ldsbuf[61440];
  const char* LB = (const char*)ldsbuf;
  const int K = g.K, NT = K / 64;
  const size_t Kb = (size_t)K * 2;
  int tid = threadIdx.x, wave = tid >> 6, lane = tid & 63;
  int quad = lane >> 4, l15 = lane & 15;
  int wm = wave >> 2, wn = wave & 3;  // 2M x 4N wave grid; per-wave C = 128x96

  // XCD-aware swizzle (256 % 8 == 0): each XCD gets a contiguous 32-block chunk
  int bid = blockIdx.x;
  int wg = (bid & 7) * 32 + (bid >> 3);
  int by = wg >> 4, bx = wg & 15;   // 16 x 16 tiles
  int m0 = by * 256, n0f = bx * 384;

  // staging: thread covers row r0 (+128/s); source col-block inverse-swizzled
  int r0 = tid >> 2;
  int cby = (((tid & 3) ^ ((tid >> 3) & 3)) * 16);
  const char* gA = (const char*)g.A + (size_t)(m0 + r0) * Kb + cby;
  const char* gB = (const char*)g.Bt + (size_t)(n0f + r0) * Kb + cby;

  auto stageA = [&](int slot, int t, int kh) {
    const char* src = gA + (size_t)t * 128 + kh * 64;
    u16* dst = &ldsbuf[slot * 8192 + tid * 8];
    cp16(src, dst);
    cp16(src + (size_t)128 * Kb, dst + 4096);
  };
  auto stageB = [&](int slot, int t, int kh) {
    const char* src = gB + (size_t)t * 128 + kh * 64;
    u16* dst = &ldsbuf[24576 + slot * 12288 + tid * 8];
    cp16(src, dst);
    cp16(src + (size_t)128 * Kb, dst + 4096);
    cp16(src + (size_t)256 * Kb, dst + 8192);
  };

  f32x4 acc0[4][6], acc1[4][6];
#pragma unroll
  for (int i = 0; i < 4; i++)
#pragma unroll
    for (int j = 0; j < 6; j++) {
      acc0[i][j] = (f32x4){0.f, 0.f, 0.f, 0.f};
      acc1[i][j] = (f32x4){0.f, 0.f, 0.f, 0.f};
    }

  // frag byte offsets within a unit: row*64 + swizzled slot*16
  int rsw = (l15 >> 1) & 3;
  int rA = (wm * 128 + l15) * 64 + ((quad ^ rsw) * 16);  // + mq*4096 + i*1024
  int rB = (wn * 96 + l15) * 64 + ((quad ^ rsw) * 16);   // + j*1024

  // prologue: stage tile 0 (units into slots 0,0,1,1)
  stageA(0, 0, 0);
  stageB(0, 0, 0);
  stageA(1, 0, 1);
  stageB(1, 0, 1);

  short8 bf[6];
  int u0 = 0;
  for (int t = 0; t < NT; ++t) {
    int u1 = u0 + 1; if (u1 == 3) u1 = 0;
    int u2 = u1 + 1; if (u2 == 3) u2 = 0;
    bool pf = (t + 1 < NT);
    const char* aK0 = LB + u0 * 16384;
    const char* aK1 = LB + u1 * 16384;
    const char* bK0 = LB + 49152 + u0 * 24576;
    const char* bK1 = LB + 49152 + u1 * 24576;

    // ---- phase 0: (mq=0, kh=0); stage A(t+1,0) -> u2 ----
    asm volatile("s_waitcnt vmcnt(5)" ::: "memory");
    __builtin_amdgcn_s_barrier();
    __builtin_amdgcn_sched_barrier(0);
    if (pf) stageA(u2, t + 1, 0);
    {
      short8 av[4];
#pragma unroll
      for (int i = 0; i < 4; i++) av[i] = *(const short8*)(aK0 + rA + i * 1024);
#pragma unroll
      for (int j = 0; j < 6; j++) bf[j] = *(const short8*)(bK0 + rB + j * 1024);
      __builtin_amdgcn_s_setprio(1);
#pragma unroll
      for (int i = 0; i < 4; i++)
#pragma unroll
        for (int j = 0; j < 6; j++) acc0[i][j] = mfma16(av[i], bf[j], acc0[i][j]);
      __builtin_amdgcn_s_setprio(0);
    }

    // ---- phase 1: (mq=1, kh=0); stage B(t+1,0) -> u2 ----
    asm volatile("s_waitcnt vmcnt(5)" ::: "memory");
    __builtin_amdgcn_s_barrier();
    __builtin_amdgcn_sched_barrier(0);
    if (pf) stageB(u2, t + 1, 0);
    {
      short8 av[4];
#pragma unroll
      for (int i = 0; i < 4; i++) av[i] = *(const short8*)(aK0 + rA + 4096 + i * 1024);
      __builtin_amdgcn_s_setprio(1);
#pragma unroll
      for (int i = 0; i < 4; i++)
#pragma unroll
        for (int j = 0; j < 6; j++) acc1[i][j] = mfma16(av[i], bf[j], acc1[i][j]);
      __builtin_amdgcn_s_setprio(0);
    }

    // ---- phase 2: (mq=0, kh=1); stage A(t+1,1) -> u0 ----
    if (t == NT - 1) asm volatile("s_waitcnt vmcnt(0)" ::: "memory");
    else asm volatile("s_waitcnt vmcnt(5)" ::: "memory");
    __builtin_amdgcn_s_barrier();
    __builtin_amdgcn_sched_barrier(0);
    if (pf) stageA(u0, t + 1, 1);
    {
      short8 av[4];
#pragma unroll
      for (int i = 0; i < 4; i++) av[i] = *(const short8*)(aK1 + rA + i * 1024);
#pragma unroll
      for (int j = 0; j < 6; j++) bf[j] = *(const short8*)(bK1 + rB + j * 1024);
      __builtin_amdgcn_s_setprio(1);
#pragma unroll
      for (int i = 0; i < 4; i++)
#pragma unroll
        for (int j = 0; j < 6; j++) acc0[i][j] = mfma16(av[i], bf[j], acc0[i][j]);
      __builtin_amdgcn_s_setprio(0);
    }

    // ---- phase 3: (mq=1, kh=1); stage B(t+1,1) -> u0 ----
    asm volatile("s_waitcnt vmcnt(5)" ::: "memory");
    __builtin_amdgcn_s_barrier();
    __builtin_amdgcn_sched_barrier(0);
    if (pf) stageB(u0, t + 1, 1);
    {
      short8 av[4];
#pragma unroll
      for (int i = 0; i < 4; i++) av[i] = *(const short8*)(aK1 + rA + 4096 + i * 1024);
      __builtin_amdgcn_s_setprio(1);
#pragma unroll
      for (int i = 0; i < 4; i++)
#pragma unroll
        for (int j = 0; j < 6; j++) acc1[i][j] = mfma16(av[i], bf[j], acc1[i][j]);
      __builtin_amdgcn_s_setprio(0);
    }

    u0 = u2;
  }

  // epilogue: per-fragment z selection across the q/k/v boundary
#pragma unroll
  for (int mq = 0; mq < 2; mq++) {
#pragma unroll
    for (int i = 0; i < 4; i++)
#pragma unroll
      for (int j = 0; j < 6; j++) {
        f32x4 a = mq ? acc1[i][j] : acc0[i][j];
        int row = m0 + wm * 128 + mq * 64 + i * 16 + quad * 4;
        int colg = n0f + wn * 96 + j * 16;
        int z = colg >> 11;
        u16* Cz = g.C + (size_t)z * ((size_t)Mrows * 2048);
        int col = (colg & 2047) + l15;
#pragma unroll
        for (int r = 0; r < 4; r++) {
          float v = a[r];
          if (z == 2) v = v / (1.f + __expf(-v));  // silu (v-projection)
          Cz[(size_t)(row + r) * 2048 + col] = f2b(v);
        }
      }
  }
}

// ---------------- Wo GEMM: 128x256 tile, 4-phase unit pipeline, f32 out ----------
// Verified r8 template port (grid 256 = 1/CU, vmcnt(3) counted, swizzle pair).
struct GemmoArgs { const u16* A; const u16* Bt; float* C; int K; };

__global__ __launch_bounds__(512, 2) void k_gemmo(GemmoArgs g) {
  // A slots: 3 x 8192B at 0; B slots: 3 x 16384B at 24576. Total 73728B.
  __shared__ u16 ldsbuf[36864];
  const char* LB = (const char*)ldsbuf;
  const int K = g.K, NT = K / 64;
  const size_t Kb = (size_t)K * 2;
  int tid = threadIdx.x, wave = tid >> 6, lane = tid & 63;
  int quad = lane >> 4, l15 = lane & 15;
  int wm = wave >> 2, wn = wave & 3;  // 2M x 4N; per-wave C = 64x64

  // XCD swizzle: chunk = one bx column (B-panel 2MB L2-resident per XCD)
  int bid = blockIdx.x;
  int wg = (bid & 7) * 32 + (bid >> 3);
  int bx = wg >> 5, by = wg & 31;
  int m0 = by * 128, n0 = bx * 256;

  int r0 = tid >> 2;
  int cby = (((tid & 3) ^ ((tid >> 3) & 3)) * 16);
  const char* gA = (const char*)g.A + (size_t)(m0 + r0) * Kb + cby;
  const char* gB = (const char*)g.Bt + (size_t)(n0 + r0) * Kb + cby;

  auto stageA = [&](int slot, int t, int kh) {
    const char* src = gA + (size_t)t * 128 + kh * 64;
    cp16(src, &ldsbuf[slot * 4096 + tid * 8]);
  };
  auto stageB = [&](int slot, int t, int kh) {
    const char* src = gB + (size_t)t * 128 + kh * 64;
    u16* dst = &ldsbuf[12288 + slot * 8192 + tid * 8];
    cp16(src, dst);
    cp16(src + (size_t)128 * Kb, dst + 4096);
  };

  f32x4 acc[4][4];
#pragma unroll
  for (int i = 0; i < 4; i++)
#pragma unroll
    for (int j = 0; j < 4; j++) acc[i][j] = (f32x4){0.f, 0.f, 0.f, 0.f};

  int rsw = (l15 >> 1) & 3;
  int rA = (wm * 64 + l15) * 64 + ((quad ^ rsw) * 16);  // + i*1024
  int rB = (wn * 64 + l15) * 64 + ((quad ^ rsw) * 16);  // + (jh*2+j)*1024

  stageA(0, 0, 0);
  stageB(0, 0, 0);
  stageA(1, 0, 1);
  stageB(1, 0, 1);

  short8 av[4];
  int u0 = 0;
  for (int t = 0; t < NT; ++t) {
    int u1 = u0 + 1; if (u1 == 3) u1 = 0;
    int u2 = u1 + 1; if (u2 == 3) u2 = 0;
    bool pf = (t + 1 < NT);
    const char* aK0 = LB + u0 * 8192;
    const char* aK1 = LB + u1 * 8192;
    const char* bK0 = LB + 24576 + u0 * 16384;
    const char* bK1 = LB + 24576 + u1 * 16384;

    // ---- phase 0: (kh0, jh0); stage A(t+1,0) -> u2 ----
    asm volatile("s_waitcnt vmcnt(3)" ::: "memory");
    __builtin_amdgcn_s_barrier();
    __builtin_amdgcn_sched_barrier(0);
    if (pf) stageA(u2, t + 1, 0);
    {
      short8 bv[2];
#pragma unroll
      for (int i = 0; i < 4; i++) av[i] = *(const short8*)(aK0 + rA + i * 1024);
#pragma unroll
      for (int j = 0; j < 2; j++) bv[j] = *(const short8*)(bK0 + rB + j * 1024);
      __builtin_amdgcn_s_setprio(1);
#pragma unroll
      for (int i = 0; i < 4; i++)
#pragma unroll
        for (int j = 0; j < 2; j++) acc[i][j] = mfma16(av[i], bv[j], acc[i][j]);
      __builtin_amdgcn_s_setprio(0);
    }

    // ---- phase 1: (kh0, jh1); stage B(t+1,0) -> u2 ----
    asm volatile("s_waitcnt vmcnt(3)" ::: "memory");
    __builtin_amdgcn_s_barrier();
    __builtin_amdgcn_sched_barrier(0);
    if (pf) stageB(u2, t + 1, 0);
    {
      short8 bv[2];
#pragma unroll
      for (int j = 0; j < 2; j++) bv[j] = *(const short8*)(bK0 + rB + (2 + j) * 1024);
      __builtin_amdgcn_s_setprio(1);
#pragma unroll
      for (int i = 0; i < 4; i++)
#pragma unroll
        for (int j = 0; j < 2; j++) acc[i][2 + j] = mfma16(av[i], bv[j], acc[i][2 + j]);
      __builtin_amdgcn_s_setprio(0);
    }

    // ---- phase 2: (kh1, jh0); stage A(t+1,1) -> u0 ----
    if (t == NT - 1) asm volatile("s_waitcnt vmcnt(0)" ::: "memory");
    else asm volatile("s_waitcnt vmcnt(3)" ::: "memory");
    __builtin_amdgcn_s_barrier();
    __builtin_amdgcn_sched_barrier(0);
    if (pf) stageA(u0, t + 1, 1);
    {
      short8 bv[2];
#pragma unroll
      for (int i = 0; i < 4; i++) av[i] = *(const short8*)(aK1 + rA + i * 1024);
#pragma unroll
      for (int j = 0; j < 2; j++) bv[j] = *(const short8*)(bK1 + rB + j * 1024);
      __builtin_amdgcn_s_setprio(1);
#pragma unroll
      for (int i = 0; i < 4; i++)
#pragma unroll
        for (int j = 0; j < 2; j++) acc[i][j] = mfma16(av[i], bv[j], acc[i][j]);
      __builtin_amdgcn_s_setprio(0);
    }

    // ---- phase 3: (kh1, jh1); stage B(t+1,1) -> u0 ----
    asm volatile("s_waitcnt vmcnt(3)" ::: "memory");
    __builtin_amdgcn_s_barrier();
    __builtin_amdgcn_sched_barrier(0);
    if (pf) stageB(u0, t + 1, 1);
    {
      short8 bv[2];
#pragma unroll
      for (int j = 0; j < 2; j++) bv[j] = *(const short8*)(bK1 + rB + (2 + j) * 1024);
      __builtin_amdgcn_s_setprio(1);
#pragma unroll
      for (int i = 0; i < 4; i++)
#pragma unroll
        for (int j = 0; j < 2; j++) acc[i][2 + j] = mfma16(av[i], bv[j], acc[i][2 + j]);
      __builtin_amdgcn_s_setprio(0);
    }

    u0 = u2;
  }

  // epilogue: f32 out
#pragma unroll
  for (int i = 0; i < 4; i++)
#pragma unroll
    for (int j = 0; j < 4; j++) {
      int row = m0 + wm * 64 + i * 16 + quad * 4;
      int col = n0 + wn * 64 + j * 16 + l15;
#pragma unroll
      for (int r = 0; r < 4; r++)
        g.C[(size_t)(row + r) * 2048 + col] = acc[i][j][r];
    }
}

// ---------------- per-chunk precompute + FUSED l2-norm ----------------
constexpr int ST = 72;
__global__ __launch_bounds__(256, 4) void k_pre(
    const float* __restrict__ beta_g,
    const u16* __restrict__ qn, const u16* __restrict__ kn, const u16* __restrict__ vn,
    u16* __restrict__ W2g, u16* __restrict__ Ug, u16* __restrict__ Gg, u16* __restrict__ KTg,
    u16* __restrict__ Qg) {
  __shared__ float beta_s[64];
  __shared__ float rnk_s[64], rnq_s[64];
  __shared__ u16 mats[4 * 64 * ST];
  int gid = blockIdx.x;
  int c = gid & 31, h = (gid >> 5) & 15, b = gid >> 9;
  int tid = threadIdx.x;
  int l0 = c * 64;

  int wave = tid >> 6, lane = tid & 63, quad = lane >> 4, l15 = lane & 15;
  u16 *Br = mats, *Bc = mats + 64 * ST, *M0 = mats + 2 * 64 * ST, *M1 = mats + 3 * 64 * ST;

  // row norms for this block's 64 tokens (rows wave*16+l15, 4-lane spread)
  short8 bfr[4], qfr[4];
  {
    int row = wave * 16 + l15;
    const u16* krow = kn + (size_t)(b * Ln + l0 + row) * Dn + h * 128;
    const u16* qrow = qn + (size_t)(b * Ln + l0 + row) * Dn + h * 128;
    float ssk = 0.f, ssq = 0.f;
#pragma unroll
    for (int s = 0; s < 4; s++) {
      bfr[s] = *(const short8*)&krow[quad * 8 + 32 * s];
      qfr[s] = *(const short8*)&qrow[quad * 8 + 32 * s];
#pragma unroll
      for (int e = 0; e < 8; e++) {
        float xk = b2f((u16)bfr[s][e]), xq = b2f((u16)qfr[s][e]);
        ssk += xk * xk; ssq += xq * xq;
      }
    }
    ssk += __shfl_xor(ssk, 16, 64); ssk += __shfl_xor(ssk, 32, 64);
    ssq += __shfl_xor(ssq, 16, 64); ssq += __shfl_xor(ssq, 32, 64);
    float rk = 1.f / fmaxf(sqrtf(ssk), 1e-12f);
    float rq = 0.08838834764831845f / fmaxf(sqrtf(ssq), 1e-12f);  // dh^-0.5 folded
    if (quad == 0) { rnk_s[row] = rk; rnq_s[row] = rq; }
#pragma unroll
    for (int s = 0; s < 4; s++) {
      bfr[s] = scale8(bfr[s], rk);
      *(short8*)&Qg[(size_t)gid * 8192 + (size_t)row * 128 + quad * 8 + 32 * s] =
          scale8(qfr[s], rq);
    }
  }
  if (tid < 64) beta_s[tid] = beta_g[(size_t)(b * Hn + h) * Ln + l0 + tid];
  __syncthreads();

  // P1: A_full = Kn Kn^T, G = tril(Qn Kn^T); B=-strict_tril(diag(beta)A), M=I+B
  {
#pragma unroll
    for (int mt = 0; mt < 4; ++mt) {
      const u16* arow_k = kn + (size_t)(b * Ln + l0 + mt * 16 + l15) * Dn + h * 128;
      const u16* arow_q = qn + (size_t)(b * Ln + l0 + mt * 16 + l15) * Dn + h * 128;
      float rkA = rnk_s[mt * 16 + l15], rqA = rnq_s[mt * 16 + l15];
      f32x4 accA = {0.f, 0.f, 0.f, 0.f}, accG = {0.f, 0.f, 0.f, 0.f};
#pragma unroll
      for (int s = 0; s < 4; s++) {
        short8 ak = scale8(*(const short8*)&arow_k[quad * 8 + 32 * s], rkA);
        short8 aq = scale8(*(const short8*)&arow_q[quad * 8 + 32 * s], rqA);
        accA = mfma16(ak, bfr[s], accA);
        accG = mfma16(aq, bfr[s], accG);
      }
      int t = wave * 16 + l15;
#pragma unroll
      for (int r = 0; r < 4; r++) {
        int i = mt * 16 + quad * 4 + r;
        u16 nb = f2b((t < i) ? -beta_s[i] * accA[r] : 0.f);
        Br[i * ST + t] = nb;
        Bc[t * ST + i] = nb;
        M0[i * ST + t] = (t == i) ? f2b(1.f) : nb;
        Gg[(size_t)gid * 4096 + (size_t)i * 64 + t] = f2b((t <= i) ? accG[r] : 0.f);
      }
    }
  }
  __syncthreads();

  // P2: Minv = (I+B)(I+B^2)(I+B^4)(I+B^8)(I+B^16)(I+B^32)
  u16 *Mc = M0, *Mn = M1;
#pragma unroll
  for (int it = 0; it < 5; ++it) {
    const int tT = (it < 3) ? 0 : ((it == 3) ? 1 : 2);
    const int tI = (it < 4) ? 0 : 1;
    short8 bb[2];
#pragma unroll
    for (int s = 0; s < 2; s++) bb[s] = *(const short8*)&Bc[(wave * 16 + l15) * ST + quad * 8 + 32 * s];
    f32x4 accT[4];
#pragma unroll
    for (int mt = 0; mt < 4; mt++) {
      accT[mt] = (f32x4){0.f, 0.f, 0.f, 0.f};
      if (mt - wave >= tT) {
#pragma unroll
        for (int s = 0; s < 2; s++) {
          short8 af = *(const short8*)&Br[(mt * 16 + l15) * ST + quad * 8 + 32 * s];
          accT[mt] = mfma16(af, bb[s], accT[mt]);
        }
      }
    }
    __syncthreads();  // all lanes done reading Br/Bc -> safe to overwrite
#pragma unroll
    for (int mt = 0; mt < 4; mt++) {
      if (mt - wave >= tI) {
#pragma unroll
        for (int r = 0; r < 4; r++) {
          int i = mt * 16 + quad * 4 + r, t = wave * 16 + l15;
          u16 v = f2b(accT[mt][r]);
          Br[i * ST + t] = v;
          Bc[t * ST + i] = v;
        }
      }
    }
    __syncthreads();  // T visible
    short8 tb[2];
#pragma unroll
    for (int s = 0; s < 2; s++) tb[s] = *(const short8*)&Bc[(wave * 16 + l15) * ST + quad * 8 + 32 * s];
#pragma unroll
    for (int mt = 0; mt < 4; mt++) {
      if (mt - wave >= tT) {
        f32x4 a;
#pragma unroll
        for (int r = 0; r < 4; r++) a[r] = b2f(Mc[(mt * 16 + quad * 4 + r) * ST + wave * 16 + l15]);
#pragma unroll
        for (int s = 0; s < 2; s++) {
          short8 af = *(const short8*)&Mc[(mt * 16 + l15) * ST + quad * 8 + 32 * s];
          a = mfma16(af, tb[s], a);
        }
#pragma unroll
        for (int r = 0; r < 4; r++) Mn[(mt * 16 + quad * 4 + r) * ST + wave * 16 + l15] = f2b(a[r]);
      } else {
#pragma unroll
        for (int r = 0; r < 4; r++)
          Mn[(mt * 16 + quad * 4 + r) * ST + wave * 16 + l15] =
              Mc[(mt * 16 + quad * 4 + r) * ST + wave * 16 + l15];
      }
    }
    u16* tmp = Mc; Mc = Mn; Mn = tmp;
  }
  __syncthreads();  // drain last M-update before P3 reuses slots

  // P3 (vectorized): Mb = Minv*diag(beta); XT = normalized K^T (pass0) / raw V^T
  // (pass1); KTg coalesced copy of normalized K^T.
  u16* XT = mats;
  u16* Mb = Mn;  // free slot after odd number of swaps
  for (int idx = tid; idx < 512; idx += 256) {
    int i = idx >> 3, t8 = (idx & 7) * 8;
    short8 m8 = *(const short8*)&Mc[i * ST + t8];
    short8 o8;
#pragma unroll
    for (int e = 0; e < 8; e++) o8[e] = (short)f2b(b2f((u16)m8[e]) * beta_s[t8 + e]);
    *(short8*)&Mb[i * ST + t8] = o8;
  }
  int tv = tid & 63, dk0 = (tid >> 6) * 32;  // lane->token row, wave->dk block
  for (int pass = 0; pass < 2; ++pass) {
    const u16* src = pass ? vn : kn;
    const u16* srow = src + (size_t)(b * Ln + l0 + tv) * Dn + h * 128 + dk0;
    float rsc = pass ? 1.f : rnk_s[tv];
#pragma unroll
    for (int s = 0; s < 4; s++) {
      short8 vv = *(const short8*)&srow[s * 8];
      if (!pass) vv = scale8(vv, rsc);
#pragma unroll
      for (int e = 0; e < 8; e++) XT[(dk0 + s * 8 + e) * ST + tv] = (u16)vv[e];
    }
    __syncthreads();
    if (pass == 0) {
#pragma unroll
      for (int it2 = 0; it2 < 4; it2++) {
        int idx = tid + it2 * 256;
        int dk = idx >> 3, t0 = (idx & 7) * 8;
        *(short8*)&KTg[(size_t)gid * 8192 + dk * 64 + t0] =
            *(const short8*)&XT[dk * ST + t0];
      }
    }
    u16* dst = pass ? Ug : W2g;
#pragma unroll
    for (int half = 0; half < 2; ++half) {
      int nt = wave + half * 4;
      short8 bx[2];
#pragma unroll
      for (int s = 0; s < 2; s++) bx[s] = *(const short8*)&XT[(nt * 16 + l15) * ST + quad * 8 + 32 * s];
#pragma unroll
      for (int mt = 0; mt < 4; mt++) {
        f32x4 a = {0.f, 0.f, 0.f, 0.f};
#pragma unroll
        for (int s = 0; s < 2; s++) {
          short8 af = *(const short8*)&Mb[(mt * 16 + l15) * ST + quad * 8 + 32 * s];
          a = mfma16(af, bx[s], a);
        }
#pragma unroll
        for (int r = 0; r < 4; r++)
          dst[(size_t)gid * 8192 + (size_t)(mt * 16 + quad * 4 + r) * 128 + nt * 16 + l15] = f2b(a[r]);
      }
    }
    __syncthreads();
  }
}

// ---------------- sequential chunk scan (per b,h and 16-wide v-slice) ----------------
struct Frg { short8 w2[4], qf[4], gf[2], k0[2], k1[2]; float u[4]; };

__global__ __launch_bounds__(256) void k_scan(
    const u16* __restrict__ Qg, const u16* __restrict__ W2g, const u16* __restrict__ Ug,
    const u16* __restrict__ Gg, const u16* __restrict__ KTg, u16* __restrict__ Og) {
  constexpr int SST = 136, DST = 104;
  __shared__ u16 Sb[16 * SST];  // S^T slice, bf16 shadow: [v][dk]
  __shared__ u16 Db[16 * DST];  // Delta^T slice: [v][t]
  int bh = blockIdx.x, sl = blockIdx.y;
  int b = bh >> 4, h = bh & 15, c0 = sl * 16;
  int tid = threadIdx.x, wave = tid >> 6, lane = tid & 63, quad = lane >> 4, l15 = lane & 15;
  for (int i = tid; i < 16 * SST; i += 256) Sb[i] = 0;
  f32x4 accS0 = {0.f, 0.f, 0.f, 0.f}, accS1 = {0.f, 0.f, 0.f, 0.f};  // fp32 master state
  __syncthreads();

  auto load_frags = [&](Frg& F, int ci) {
    size_t ck = (size_t)bh * NCK + ci;
    const u16* w2row = W2g + ck * 8192 + (size_t)(wave * 16 + l15) * 128;
    const u16* qrow = Qg + ck * 8192 + (size_t)(wave * 16 + l15) * 128;
#pragma unroll
    for (int s = 0; s < 4; s++) {
      F.w2[s] = *(const short8*)&w2row[quad * 8 + 32 * s];
      F.qf[s] = *(const short8*)&qrow[quad * 8 + 32 * s];
    }
    const u16* grow = Gg + ck * 4096 + (size_t)(wave * 16 + l15) * 64;
    const u16* kt0 = KTg + ck * 8192 + (size_t)(wave * 16 + l15) * 64;
    const u16* kt1 = KTg + ck * 8192 + (size_t)((wave + 4) * 16 + l15) * 64;
#pragma unroll
    for (int s = 0; s < 2; s++) {
      F.gf[s] = *(const short8*)&grow[quad * 8 + 32 * s];
      F.k0[s] = *(const short8*)&kt0[quad * 8 + 32 * s];
      F.k1[s] = *(const short8*)&kt1[quad * 8 + 32 * s];
    }
    const u16* urow = Ug + ck * 8192 + (size_t)(wave * 16 + quad * 4) * 128 + c0 + l15;
#pragma unroll
    for (int r = 0; r < 4; r++) F.u[r] = b2f(urow[(size_t)r * 128]);
  };

  auto compute = [&](const Frg& F, int ci) {
    f32x4 accT = {0.f, 0.f, 0.f, 0.f}, accO = {0.f, 0.f, 0.f, 0.f};
#pragma unroll
    for (int s = 0; s < 4; s++) {
      short8 sf = *(const short8*)&Sb[l15 * SST + quad * 8 + 32 * s];
      accT = mfma16(F.w2[s], sf, accT);   // W2 @ S0
      accO = mfma16(F.qf[s], sf, accO);   // Q @ S0
    }
#pragma unroll
    for (int r = 0; r < 4; r++) {
      float d = F.u[r] - accT[r];         // Delta = U - W2@S0
      Db[l15 * DST + wave * 16 + quad * 4 + r] = f2b(d);
    }
    __syncthreads();
#pragma unroll
    for (int s = 0; s < 2; s++) {
      short8 df = *(const short8*)&Db[l15 * DST + quad * 8 + 32 * s];
      accO = mfma16(F.gf[s], df, accO);   // O += tril(QK^T) @ Delta
      accS0 = mfma16(F.k0[s], df, accS0); // S += K^T @ Delta
      accS1 = mfma16(F.k1[s], df, accS1);
    }
    u16* orow = Og + (size_t)(b * Ln + ci * 64 + wave * 16 + quad * 4) * Dn + h * 128 + c0 + l15;
#pragma unroll
    for (int r = 0; r < 4; r++) orow[(size_t)r * Dn] = f2b(accO[r]);
#pragma unroll
    for (int r = 0; r < 4; r++) {
      Sb[l15 * SST + wave * 16 + quad * 4 + r] = f2b(accS0[r]);
      Sb[l15 * SST + (wave + 4) * 16 + quad * 4 + r] = f2b(accS1[r]);
    }
    __syncthreads();
  };

  Frg FA, FB;
  load_frags(FA, 0);
  for (int ci = 0; ci < NCK; ci += 2) {
    load_frags(FB, ci + 1);
    compute(FA, ci);
    if (ci + 2 < NCK) load_frags(FA, ci + 2);
    compute(FB, ci + 1);
  }
}

// ---------------- RMSNorm over head dim (vectorized: 2 rows/wave, 8B/lane) -------
__global__ void k_rms(const u16* __restrict__ Og, const float* __restrict__ w, u16* __restrict__ out) {
  int tid = threadIdx.x, wave = tid >> 6, lane = tid & 63;
  int half = lane >> 5, l32 = lane & 31;
  size_t row = (size_t)blockIdx.x * 8 + wave * 2 + half;
  const u16* p = Og + row * 128 + l32 * 4;
  u32 u0 = *(const u32*)&p[0], u1 = *(const u32*)&p[2];
  float x0 = b2f((u16)(u0 & 0xffff)), x1 = b2f((u16)(u0 >> 16));
  float x2 = b2f((u16)(u1 & 0xffff)), x3 = b2f((u16)(u1 >> 16));
  float ss = x0 * x0 + x1 * x1 + x2 * x2 + x3 * x3;
#pragma unroll
  for (int o = 16; o > 0; o >>= 1) ss += __shfl_xor(ss, o, 64);  // stays in 32-half
  float sc = rsqrtf(ss * (1.f / 128.f) + 1e-5f);
  float4 wv = *(const float4*)&w[l32 * 4];
  u32 o0 = (u32)f2b(x0 * sc * wv.x) | ((u32)f2b(x1 * sc * wv.y) << 16);
  u32 o1 = (u32)f2b(x2 * sc * wv.z) | ((u32)f2b(x3 * sc * wv.w) << 16);
  u32* d = (u32*)&out[row * 128 + l32 * 4];
  d[0] = o0; d[1] = o1;
}

// ---------------- host ----------------
extern "C" void kernel_launch(void* const* d_in, const int* in_sizes, int n_in,
                              void* d_out, int out_size, void* d_ws, size_t ws_size,
                              hipStream_t stream) {
  (void)in_sizes; (void)n_in; (void)out_size; (void)ws_size;
  const float* hs_f = (const float*)d_in[0];
  const float* Wq = (const float*)d_in[1];
  const float* Wk = (const float*)d_in[2];
  const float* Wv = (const float*)d_in[3];
  const float* Wb = (const float*)d_in[4];
  const float* onw = (const float*)d_in[5];
  const float* Wo = (const float*)d_in[6];

  char* ws = (char*)d_ws;
  size_t off = 0;
  auto alloc = [&](size_t bytes) -> void* {
    void* p = ws + off;
    off += (bytes + 255) & ~(size_t)255;
    return p;
  };
  const size_t WB = (size_t)2048 * 2048 * 2;
  const size_t XB = (size_t)4096 * 2048 * 2;
  u16* WqT = (u16*)alloc(WB);   // WqT|WkT|WvT contiguous => fused Bt [6144][2048]
  u16* WkT = (u16*)alloc(WB);
  u16* WvT = (u16*)alloc(WB);
  u16* WoT = (u16*)alloc(WB);
  u16* WbT = (u16*)alloc((size_t)16 * 2048 * 2);
  u16* hsb = (u16*)alloc(XB);
  u16* qn  = (u16*)alloc(XB);   // qn|kn|vn contiguous => fused C
  u16* kn  = (u16*)alloc(XB);
  u16* vn  = (u16*)alloc(XB);   // reused as O after precompute
  u16* W2g = (u16*)alloc((size_t)NCHUNKS * 8192 * 2);
  u16* Ug  = (u16*)alloc((size_t)NCHUNKS * 8192 * 2);
  u16* Gg  = (u16*)alloc((size_t)NCHUNKS * 4096 * 2);
  u16* KTg = (u16*)alloc((size_t)NCHUNKS * 8192 * 2);
  u16* Qg  = (u16*)alloc((size_t)NCHUNKS * 8192 * 2);  // normalized q, chunk layout
  float* beta_g = (float*)alloc((size_t)Bn * Hn * Ln * 4);
  u16* Og = vn;       // v dead after precompute
  u16* onorm = qn;    // q dead after precompute (scan reads Qg)

  // 0) downcast hidden_states
  hipLaunchKernelGGL(k_cvt, dim3(Mrows * Dn / 8 / 256), dim3(256), 0, stream, hs_f, hsb, Mrows * Dn / 8);

  // 1) big weight transposes (vectorized) + Wb (small path)
  Trans2Args t2;
  t2.src[0] = Wq; t2.dst[0] = WqT;
  t2.src[1] = Wk; t2.dst[1] = WkT;
  t2.src[2] = Wv; t2.dst[2] = WvT;
  t2.src[3] = Wo; t2.dst[3] = WoT;
  hipLaunchKernelGGL(k_trans2, dim3(32, 32, 4), dim3(256), 0, stream, t2);
  TransArgs ta;
  ta.src[0] = Wb; ta.dst[0] = WbT; ta.rows[0] = 2048; ta.cols[0] = 16;
  hipLaunchKernelGGL(k_trans, dim3(1, 64, 1), dim3(32, 8), 0, stream, ta);

  // 1b) beta for all heads (K-split, 256 blocks)
  hipLaunchKernelGGL(k_beta, dim3(Mrows / 16), dim3(256), 0, stream, hsb, WbT, beta_g);

  // 2) fused q/k/v projection: one 4096x6144x2048 GEMM, 256x384 tiles, grid-exact 256
  {
    Gemm2Args g2;
    g2.A = hsb; g2.Bt = WqT; g2.C = qn; g2.K = 2048;
    hipLaunchKernelGGL(k_gemm2, dim3(256), dim3(512), 0, stream, g2);
  }

  // 3) chunk precompute + fused l2-norm
  hipLaunchKernelGGL(k_pre, dim3(NCHUNKS), dim3(256), 0, stream,
                     beta_g, qn, kn, vn, W2g, Ug, Gg, KTg, Qg);

  // 4) sequential scan (reads normalized q from Qg chunk layout)
  hipLaunchKernelGGL(k_scan, dim3(32, 8), dim3(256), 0, stream,
                     Qg, W2g, Ug, Gg, KTg, Og);

  // 5) RMSNorm (2 rows/wave, 8B/lane)
  hipLaunchKernelGGL(k_rms, dim3(8192), dim3(256), 0, stream, Og, onw, onorm);

  // 6) output projection (fp32 out -> d_out), 4-phase 128x256 pipeline, grid 256
  {
    GemmoArgs go;
    go.A = onorm; go.Bt = WoT; go.C = (float*)d_out; go.K = 2048;
    hipLaunchKernelGGL(k_gemmo, dim3(256), dim3(512), 0, stream, go);
  }
}

// Round 12
// 409.870 us; speedup vs baseline: 1.0727x; 1.0126x over previous
//
#include <hip/hip_runtime.h>
#include <hip/hip_bf16.h>
#include <cstdint>

#define DEV static __device__ __forceinline__

typedef unsigned short u16;
typedef unsigned int u32;
typedef __attribute__((ext_vector_type(8))) short short8;
typedef __attribute__((ext_vector_type(4))) float f32x4;

constexpr int Bn = 2, Ln = 2048, Dn = 2048, Hn = 16;
constexpr int Mrows = Bn * Ln;          // 4096
constexpr int CHK = 64, NCK = Ln / CHK; // chunk=64, 32 chunks/seq
constexpr int NCHUNKS = Bn * Hn * NCK;  // 1024

DEV float b2f(u16 s) { union { float f; u32 u; } x; x.u = ((u32)s) << 16; return x.f; }
DEV u16 f2b(float f) {
  union { float f; u32 u; } x; x.f = f; u32 u = x.u;
  return (u16)((u + 0x7fffu + ((u >> 16) & 1u)) >> 16);  // RNE
}

DEV void cp16(const void* g, void* l) {
  __builtin_amdgcn_global_load_lds(
      (const __attribute__((address_space(1))) u32*)(unsigned long long)(g),
      (__attribute__((address_space(3))) u32*)(unsigned long long)(l), 16, 0, 0);
}

DEV f32x4 mfma16(short8 a, short8 b, f32x4 c) {
  return __builtin_amdgcn_mfma_f32_16x16x32_bf16(a, b, c, 0, 0, 0);
}

DEV short8 scale8(short8 v, float sc) {
  short8 o;
#pragma unroll
  for (int e = 0; e < 8; e++) o[e] = (short)f2b(b2f((u16)v[e]) * sc);
  return o;
}

// ---------------- fused front-end: weight transposes + hs downcast + Wb ---------
// One dispatch replaces k_cvt + k_trans2 + k_trans (launch-gap + co-scheduling).
// blocks [0,4096): 64x64 transpose tiles of Wq/Wk/Wv/Wo (z = bid>>10)
// blocks [4096,8192): hs fp32->bf16 downcast (8 elems/thread, exact cover)
// blocks [8192,8256): Wb 2048x16 transpose (32-row strips)
struct PrepArgs { const float* wsrc[5]; u16* wdst[5]; const float* hs; u16* hsb; };
__global__ __launch_bounds__(256) void k_prep(PrepArgs p) {
  __shared__ u16 tile[64 * 72];
  int bid = blockIdx.x, tid = threadIdx.x;
  if (bid < 4096) {
    int z = bid >> 10, t = bid & 1023;
    int r0 = (t >> 5) * 64, c0 = (t & 31) * 64;
    const float* src = p.wsrc[z];
    u16* dst = p.wdst[z];
    int lr = tid >> 2, lc = (tid & 3) * 16;
    const float* s = src + (size_t)(r0 + lr) * 2048 + c0 + lc;
#pragma unroll
    for (int i = 0; i < 4; i++) {
      float4 v = *(const float4*)(s + i * 4);
      tile[lr * 72 + lc + i * 4 + 0] = f2b(v.x);
      tile[lr * 72 + lc + i * 4 + 1] = f2b(v.y);
      tile[lr * 72 + lc + i * 4 + 2] = f2b(v.z);
      tile[lr * 72 + lc + i * 4 + 3] = f2b(v.w);
    }
    __syncthreads();
    int orr = tid >> 2, oc = (tid & 3) * 16;
    u16* d = dst + (size_t)(c0 + orr) * 2048 + r0 + oc;
    u16 buf[16];
#pragma unroll
    for (int e = 0; e < 16; e++) buf[e] = tile[(oc + e) * 72 + orr];
    *(short8*)(d) = *(short8*)buf;
    *(short8*)(d + 8) = *(short8*)(buf + 8);
  } else if (bid < 8192) {
    int i = (bid - 4096) * 256 + tid;  // exact: 4096*256 == Mrows*Dn/8
    const float4* s4 = (const float4*)(p.hs + (size_t)i * 8);
    float4 a = s4[0], b = s4[1];
    u16 o[8] = {f2b(a.x), f2b(a.y), f2b(a.z), f2b(a.w),
                f2b(b.x), f2b(b.y), f2b(b.z), f2b(b.w)};
    *(short8*)(p.hsb + (size_t)i * 8) = *(short8*)o;
  } else {
    // Wb 2048x16 -> WbT 16x2048, 32-row strip per block
    int r0 = (bid - 8192) * 32;
    int tx = tid & 31, ty = tid >> 5;  // 32x8
    for (int i = ty; i < 32; i += 8) {
      if (tx < 16) tile[i * 33 + tx] = f2b(p.wsrc[4][(size_t)(r0 + i) * 16 + tx]);
    }
    __syncthreads();
    for (int i = ty; i < 32; i += 8) {
      if (i < 16) p.wdst[4][(size_t)i * 2048 + r0 + tx] = tile[tx * 33 + i];
    }
  }
}

// ---------------- beta = sigmoid(hs @ Wb), K-split MFMA GEMV ----------------
__global__ __launch_bounds__(256) void k_beta(const u16* __restrict__ hs,
                                              const u16* __restrict__ WbT,
                                              float* __restrict__ beta_g) {
  __shared__ float part[256];  // [head][tokr]
  int tid = threadIdx.x, wave = tid >> 6, lane = tid & 63, quad = lane >> 4, l15 = lane & 15;
  int tok0 = blockIdx.x * 16;
  const u16* arow = hs + (size_t)(tok0 + l15) * Dn + wave * 512;   // A[m=l15][k-slice]
  const u16* brow = WbT + (size_t)l15 * Dn + wave * 512;           // B[n=head=l15][k-slice]
  f32x4 acc = {0.f, 0.f, 0.f, 0.f};
#pragma unroll
  for (int k = 0; k < 512; k += 32) {
    short8 af = *(const short8*)&arow[k + quad * 8];
    short8 bf = *(const short8*)&brow[k + quad * 8];
    acc = mfma16(af, bf, acc);
  }
  part[tid] = 0.f;
  __syncthreads();
#pragma unroll
  for (int r = 0; r < 4; r++) atomicAdd(&part[l15 * 16 + quad * 4 + r], acc[r]);
  __syncthreads();
  int h = tid >> 4, tr = tid & 15;
  int b = tok0 >> 11;
  int l = (tok0 + tr) & 2047;
  beta_g[(size_t)(b * Hn + h) * Ln + l] = 1.f / (1.f + __expf(-part[h * 16 + tr]));
}

// ---------------- fused QKV GEMM: 256x384 tile, 4-phase unit pipeline ----------------
// VERBATIM round-4 verified structure (121-123 us). FROZEN — r5/r6/r10 all showed
// restructures/ports regress; this is the session's GEMM plateau structure.
struct Gemm2Args { const u16* A; const u16* Bt; u16* C; int K; };

__global__ __launch_bounds__(512, 2) void k_gemm2(Gemm2Args g) {
  // A slots: 3 x 16384B at 0; B slots: 3 x 24576B at 49152. Total 122880B.
  __shared__ u16 ldsbuf[61440];
  const char* LB = (const char*)ldsbuf;
  const int K = g.K, NT = K / 64;
  const size_t Kb = (size_t)K * 2;
  int tid = threadIdx.x, wave = tid >> 6, lane = tid & 63;
  int quad = lane >> 4, l15 = lane & 15;
  int wm = wave >> 2, wn = wave & 3;  // 2M x 4N wave grid; per-wave C = 128x96

  // XCD-aware swizzle (256 % 8 == 0): each XCD gets a contiguous 32-block chunk
  int bid = blockIdx.x;
  int wg = (bid & 7) * 32 + (bid >> 3);
  int by = wg >> 4, bx = wg & 15;   // 16 x 16 tiles
  int m0 = by * 256, n0f = bx * 384;

  // staging: thread covers row r0 (+128/s); source col-block inverse-swizzled
  int r0 = tid >> 2;
  int cby = (((tid & 3) ^ ((tid >> 3) & 3)) * 16);
  const char* gA = (const char*)g.A + (size_t)(m0 + r0) * Kb + cby;
  const char* gB = (const char*)g.Bt + (size_t)(n0f + r0) * Kb + cby;

  auto stageA = [&](int slot, int t, int kh) {
    const char* src = gA + (size_t)t * 128 + kh * 64;
    u16* dst = &ldsbuf[slot * 8192 + tid * 8];
    cp16(src, dst);
    cp16(src + (size_t)128 * Kb, dst + 4096);
  };
  auto stageB = [&](int slot, int t, int kh) {
    const char* src = gB + (size_t)t * 128 + kh * 64;
    u16* dst = &ldsbuf[24576 + slot * 12288 + tid * 8];
    cp16(src, dst);
    cp16(src + (size_t)128 * Kb, dst + 4096);
    cp16(src + (size_t)256 * Kb, dst + 8192);
  };

  f32x4 acc0[4][6], acc1[4][6];
#pragma unroll
  for (int i = 0; i < 4; i++)
#pragma unroll
    for (int j = 0; j < 6; j++) {
      acc0[i][j] = (f32x4){0.f, 0.f, 0.f, 0.f};
      acc1[i][j] = (f32x4){0.f, 0.f, 0.f, 0.f};
    }

  // frag byte offsets within a unit: row*64 + swizzled slot*16
  int rsw = (l15 >> 1) & 3;
  int rA = (wm * 128 + l15) * 64 + ((quad ^ rsw) * 16);  // + mq*4096 + i*1024
  int rB = (wn * 96 + l15) * 64 + ((quad ^ rsw) * 16);   // + j*1024

  // prologue: stage tile 0 (units into slots 0,0,1,1)
  stageA(0, 0, 0);
  stageB(0, 0, 0);
  stageA(1, 0, 1);
  stageB(1, 0, 1);

  short8 bf[6];
  int u0 = 0;
  for (int t = 0; t < NT; ++t) {
    int u1 = u0 + 1; if (u1 == 3) u1 = 0;
    int u2 = u1 + 1; if (u2 == 3) u2 = 0;
    bool pf = (t + 1 < NT);
    const char* aK0 = LB + u0 * 16384;
    const char* aK1 = LB + u1 * 16384;
    const char* bK0 = LB + 49152 + u0 * 24576;
    const char* bK1 = LB + 49152 + u1 * 24576;

    // ---- phase 0: (mq=0, kh=0); stage A(t+1,0) -> u2 ----
    asm volatile("s_waitcnt vmcnt(5)" ::: "memory");
    __builtin_amdgcn_s_barrier();
    __builtin_amdgcn_sched_barrier(0);
    if (pf) stageA(u2, t + 1, 0);
    {
      short8 av[4];
#pragma unroll
      for (int i = 0; i < 4; i++) av[i] = *(const short8*)(aK0 + rA + i * 1024);
#pragma unroll
      for (int j = 0; j < 6; j++) bf[j] = *(const short8*)(bK0 + rB + j * 1024);
      __builtin_amdgcn_s_setprio(1);
#pragma unroll
      for (int i = 0; i < 4; i++)
#pragma unroll
        for (int j = 0; j < 6; j++) acc0[i][j] = mfma16(av[i], bf[j], acc0[i][j]);
      __builtin_amdgcn_s_setprio(0);
    }

    // ---- phase 1: (mq=1, kh=0); stage B(t+1,0) -> u2 ----
    asm volatile("s_waitcnt vmcnt(5)" ::: "memory");
    __builtin_amdgcn_s_barrier();
    __builtin_amdgcn_sched_barrier(0);
    if (pf) stageB(u2, t + 1, 0);
    {
      short8 av[4];
#pragma unroll
      for (int i = 0; i < 4; i++) av[i] = *(const short8*)(aK0 + rA + 4096 + i * 1024);
      __builtin_amdgcn_s_setprio(1);
#pragma unroll
      for (int i = 0; i < 4; i++)
#pragma unroll
        for (int j = 0; j < 6; j++) acc1[i][j] = mfma16(av[i], bf[j], acc1[i][j]);
      __builtin_amdgcn_s_setprio(0);
    }

    // ---- phase 2: (mq=0, kh=1); stage A(t+1,1) -> u0 ----
    if (t == NT - 1) asm volatile("s_waitcnt vmcnt(0)" ::: "memory");
    else asm volatile("s_waitcnt vmcnt(5)" ::: "memory");
    __builtin_amdgcn_s_barrier();
    __builtin_amdgcn_sched_barrier(0);
    if (pf) stageA(u0, t + 1, 1);
    {
      short8 av[4];
#pragma unroll
      for (int i = 0; i < 4; i++) av[i] = *(const short8*)(aK1 + rA + i * 1024);
#pragma unroll
      for (int j = 0; j < 6; j++) bf[j] = *(const short8*)(bK1 + rB + j * 1024);
      __builtin_amdgcn_s_setprio(1);
#pragma unroll
      for (int i = 0; i < 4; i++)
#pragma unroll
        for (int j = 0; j < 6; j++) acc0[i][j] = mfma16(av[i], bf[j], acc0[i][j]);
      __builtin_amdgcn_s_setprio(0);
    }

    // ---- phase 3: (mq=1, kh=1); stage B(t+1,1) -> u0 ----
    asm volatile("s_waitcnt vmcnt(5)" ::: "memory");
    __builtin_amdgcn_s_barrier();
    __builtin_amdgcn_sched_barrier(0);
    if (pf) stageB(u0, t + 1, 1);
    {
      short8 av[4];
#pragma unroll
      for (int i = 0; i < 4; i++) av[i] = *(const short8*)(aK1 + rA + 4096 + i * 1024);
      __builtin_amdgcn_s_setprio(1);
#pragma unroll
      for (int i = 0; i < 4; i++)
#pragma unroll
        for (int j = 0; j < 6; j++) acc1[i][j] = mfma16(av[i], bf[j], acc1[i][j]);
      __builtin_amdgcn_s_setprio(0);
    }

    u0 = u2;
  }

  // epilogue: per-fragment z selection across the q/k/v boundary
#pragma unroll
  for (int mq = 0; mq < 2; mq++) {
#pragma unroll
    for (int i = 0; i < 4; i++)
#pragma unroll
      for (int j = 0; j < 6; j++) {
        f32x4 a = mq ? acc1[i][j] : acc0[i][j];
        int row = m0 + wm * 128 + mq * 64 + i * 16 + quad * 4;
        int colg = n0f + wn * 96 + j * 16;
        int z = colg >> 11;
        u16* Cz = g.C + (size_t)z * ((size_t)Mrows * 2048);
        int col = (colg & 2047) + l15;
#pragma unroll
        for (int r = 0; r < 4; r++) {
          float v = a[r];
          if (z == 2) v = v / (1.f + __expf(-v));  // silu (v-projection)
          Cz[(size_t)(row + r) * 2048 + col] = f2b(v);
        }
      }
  }
}

// ---------------- Wo GEMM: 128x256 tile, 4-phase unit pipeline, f32 out ----------
struct GemmoArgs { const u16* A; const u16* Bt; float* C; int K; };

__global__ __launch_bounds__(512, 2) void k_gemmo(GemmoArgs g) {
  // A slots: 3 x 8192B at 0; B slots: 3 x 16384B at 24576. Total 73728B.
  __shared__ u16 ldsbuf[36864];
  const char* LB = (const char*)ldsbuf;
  const int K = g.K, NT = K / 64;
  const size_t Kb = (size_t)K * 2;
  int tid = threadIdx.x, wave = tid >> 6, lane = tid & 63;
  int quad = lane >> 4, l15 = lane & 15;
  int wm = wave >> 2, wn = wave & 3;  // 2M x 4N; per-wave C = 64x64

  // XCD swizzle: chunk = one bx column (B-panel 2MB L2-resident per XCD)
  int bid = blockIdx.x;
  int wg = (bid & 7) * 32 + (bid >> 3);
  int bx = wg >> 5, by = wg & 31;
  int m0 = by * 128, n0 = bx * 256;

  int r0 = tid >> 2;
  int cby = (((tid & 3) ^ ((tid >> 3) & 3)) * 16);
  const char* gA = (const char*)g.A + (size_t)(m0 + r0) * Kb + cby;
  const char* gB = (const char*)g.Bt + (size_t)(n0 + r0) * Kb + cby;

  auto stageA = [&](int slot, int t, int kh) {
    const char* src = gA + (size_t)t * 128 + kh * 64;
    cp16(src, &ldsbuf[slot * 4096 + tid * 8]);
  };
  auto stageB = [&](int slot, int t, int kh) {
    const char* src = gB + (size_t)t * 128 + kh * 64;
    u16* dst = &ldsbuf[12288 + slot * 8192 + tid * 8];
    cp16(src, dst);
    cp16(src + (size_t)128 * Kb, dst + 4096);
  };

  f32x4 acc[4][4];
#pragma unroll
  for (int i = 0; i < 4; i++)
#pragma unroll
    for (int j = 0; j < 4; j++) acc[i][j] = (f32x4){0.f, 0.f, 0.f, 0.f};

  int rsw = (l15 >> 1) & 3;
  int rA = (wm * 64 + l15) * 64 + ((quad ^ rsw) * 16);  // + i*1024
  int rB = (wn * 64 + l15) * 64 + ((quad ^ rsw) * 16);  // + (jh*2+j)*1024

  stageA(0, 0, 0);
  stageB(0, 0, 0);
  stageA(1, 0, 1);
  stageB(1, 0, 1);

  short8 av[4];
  int u0 = 0;
  for (int t = 0; t < NT; ++t) {
    int u1 = u0 + 1; if (u1 == 3) u1 = 0;
    int u2 = u1 + 1; if (u2 == 3) u2 = 0;
    bool pf = (t + 1 < NT);
    const char* aK0 = LB + u0 * 8192;
    const char* aK1 = LB + u1 * 8192;
    const char* bK0 = LB + 24576 + u0 * 16384;
    const char* bK1 = LB + 24576 + u1 * 16384;

    // ---- phase 0: (kh0, jh0); stage A(t+1,0) -> u2 ----
    asm volatile("s_waitcnt vmcnt(3)" ::: "memory");
    __builtin_amdgcn_s_barrier();
    __builtin_amdgcn_sched_barrier(0);
    if (pf) stageA(u2, t + 1, 0);
    {
      short8 bv[2];
#pragma unroll
      for (int i = 0; i < 4; i++) av[i] = *(const short8*)(aK0 + rA + i * 1024);
#pragma unroll
      for (int j = 0; j < 2; j++) bv[j] = *(const short8*)(bK0 + rB + j * 1024);
      __builtin_amdgcn_s_setprio(1);
#pragma unroll
      for (int i = 0; i < 4; i++)
#pragma unroll
        for (int j = 0; j < 2; j++) acc[i][j] = mfma16(av[i], bv[j], acc[i][j]);
      __builtin_amdgcn_s_setprio(0);
    }

    // ---- phase 1: (kh0, jh1); stage B(t+1,0) -> u2 ----
    asm volatile("s_waitcnt vmcnt(3)" ::: "memory");
    __builtin_amdgcn_s_barrier();
    __builtin_amdgcn_sched_barrier(0);
    if (pf) stageB(u2, t + 1, 0);
    {
      short8 bv[2];
#pragma unroll
      for (int j = 0; j < 2; j++) bv[j] = *(const short8*)(bK0 + rB + (2 + j) * 1024);
      __builtin_amdgcn_s_setprio(1);
#pragma unroll
      for (int i = 0; i < 4; i++)
#pragma unroll
        for (int j = 0; j < 2; j++) acc[i][2 + j] = mfma16(av[i], bv[j], acc[i][2 + j]);
      __builtin_amdgcn_s_setprio(0);
    }

    // ---- phase 2: (kh1, jh0); stage A(t+1,1) -> u0 ----
    if (t == NT - 1) asm volatile("s_waitcnt vmcnt(0)" ::: "memory");
    else asm volatile("s_waitcnt vmcnt(3)" ::: "memory");
    __builtin_amdgcn_s_barrier();
    __builtin_amdgcn_sched_barrier(0);
    if (pf) stageA(u0, t + 1, 1);
    {
      short8 bv[2];
#pragma unroll
      for (int i = 0; i < 4; i++) av[i] = *(const short8*)(aK1 + rA + i * 1024);
#pragma unroll
      for (int j = 0; j < 2; j++) bv[j] = *(const short8*)(bK1 + rB + j * 1024);
      __builtin_amdgcn_s_setprio(1);
#pragma unroll
      for (int i = 0; i < 4; i++)
#pragma unroll
        for (int j = 0; j < 2; j++) acc[i][j] = mfma16(av[i], bv[j], acc[i][j]);
      __builtin_amdgcn_s_setprio(0);
    }

    // ---- phase 3: (kh1, jh1); stage B(t+1,1) -> u0 ----
    asm volatile("s_waitcnt vmcnt(3)" ::: "memory");
    __builtin_amdgcn_s_barrier();
    __builtin_amdgcn_sched_barrier(0);
    if (pf) stageB(u0, t + 1, 1);
    {
      short8 bv[2];
#pragma unroll
      for (int j = 0; j < 2; j++) bv[j] = *(const short8*)(bK1 + rB + (2 + j) * 1024);
      __builtin_amdgcn_s_setprio(1);
#pragma unroll
      for (int i = 0; i < 4; i++)
#pragma unroll
        for (int j = 0; j < 2; j++) acc[i][2 + j] = mfma16(av[i], bv[j], acc[i][2 + j]);
      __builtin_amdgcn_s_setprio(0);
    }

    u0 = u2;
  }

  // epilogue: f32 out
#pragma unroll
  for (int i = 0; i < 4; i++)
#pragma unroll
    for (int j = 0; j < 4; j++) {
      int row = m0 + wm * 64 + i * 16 + quad * 4;
      int col = n0 + wn * 64 + j * 16 + l15;
#pragma unroll
      for (int r = 0; r < 4; r++)
        g.C[(size_t)(row + r) * 2048 + col] = acc[i][j][r];
    }
}

// ---------------- per-chunk precompute + FUSED l2-norm ----------------
constexpr int ST = 72;
__global__ __launch_bounds__(256, 4) void k_pre(
    const float* __restrict__ beta_g,
    const u16* __restrict__ qn, const u16* __restrict__ kn, const u16* __restrict__ vn,
    u16* __restrict__ W2g, u16* __restrict__ Ug, u16* __restrict__ Gg, u16* __restrict__ KTg,
    u16* __restrict__ Qg) {
  __shared__ float beta_s[64];
  __shared__ float rnk_s[64], rnq_s[64];
  __shared__ u16 mats[4 * 64 * ST];
  int gid = blockIdx.x;
  int c = gid & 31, h = (gid >> 5) & 15, b = gid >> 9;
  int tid = threadIdx.x;
  int l0 = c * 64;

  int wave = tid >> 6, lane = tid & 63, quad = lane >> 4, l15 = lane & 15;
  u16 *Br = mats, *Bc = mats + 64 * ST, *M0 = mats + 2 * 64 * ST, *M1 = mats + 3 * 64 * ST;

  // row norms for this block's 64 tokens (rows wave*16+l15, 4-lane spread)
  short8 bfr[4], qfr[4];
  {
    int row = wave * 16 + l15;
    const u16* krow = kn + (size_t)(b * Ln + l0 + row) * Dn + h * 128;
    const u16* qrow = qn + (size_t)(b * Ln + l0 + row) * Dn + h * 128;
    float ssk = 0.f, ssq = 0.f;
#pragma unroll
    for (int s = 0; s < 4; s++) {
      bfr[s] = *(const short8*)&krow[quad * 8 + 32 * s];
      qfr[s] = *(const short8*)&qrow[quad * 8 + 32 * s];
#pragma unroll
      for (int e = 0; e < 8; e++) {
        float xk = b2f((u16)bfr[s][e]), xq = b2f((u16)qfr[s][e]);
        ssk += xk * xk; ssq += xq * xq;
      }
    }
    ssk += __shfl_xor(ssk, 16, 64); ssk += __shfl_xor(ssk, 32, 64);
    ssq += __shfl_xor(ssq, 16, 64); ssq += __shfl_xor(ssq, 32, 64);
    float rk = 1.f / fmaxf(sqrtf(ssk), 1e-12f);
    float rq = 0.08838834764831845f / fmaxf(sqrtf(ssq), 1e-12f);  // dh^-0.5 folded
    if (quad == 0) { rnk_s[row] = rk; rnq_s[row] = rq; }
#pragma unroll
    for (int s = 0; s < 4; s++) {
      bfr[s] = scale8(bfr[s], rk);
      *(short8*)&Qg[(size_t)gid * 8192 + (size_t)row * 128 + quad * 8 + 32 * s] =
          scale8(qfr[s], rq);
    }
  }
  if (tid < 64) beta_s[tid] = beta_g[(size_t)(b * Hn + h) * Ln + l0 + tid];
  __syncthreads();

  // P1: A_full = Kn Kn^T, G = tril(Qn Kn^T); B=-strict_tril(diag(beta)A), M=I+B
  {
#pragma unroll
    for (int mt = 0; mt < 4; ++mt) {
      const u16* arow_k = kn + (size_t)(b * Ln + l0 + mt * 16 + l15) * Dn + h * 128;
      const u16* arow_q = qn + (size_t)(b * Ln + l0 + mt * 16 + l15) * Dn + h * 128;
      float rkA = rnk_s[mt * 16 + l15], rqA = rnq_s[mt * 16 + l15];
      f32x4 accA = {0.f, 0.f, 0.f, 0.f}, accG = {0.f, 0.f, 0.f, 0.f};
#pragma unroll
      for (int s = 0; s < 4; s++) {
        short8 ak = scale8(*(const short8*)&arow_k[quad * 8 + 32 * s], rkA);
        short8 aq = scale8(*(const short8*)&arow_q[quad * 8 + 32 * s], rqA);
        accA = mfma16(ak, bfr[s], accA);
        accG = mfma16(aq, bfr[s], accG);
      }
      int t = wave * 16 + l15;
#pragma unroll
      for (int r = 0; r < 4; r++) {
        int i = mt * 16 + quad * 4 + r;
        u16 nb = f2b((t < i) ? -beta_s[i] * accA[r] : 0.f);
        Br[i * ST + t] = nb;
        Bc[t * ST + i] = nb;
        M0[i * ST + t] = (t == i) ? f2b(1.f) : nb;
        Gg[(size_t)gid * 4096 + (size_t)i * 64 + t] = f2b((t <= i) ? accG[r] : 0.f);
      }
    }
  }
  __syncthreads();

  // P2: Minv = (I+B)(I+B^2)(I+B^4)(I+B^8)(I+B^16)(I+B^32)
  u16 *Mc = M0, *Mn = M1;
#pragma unroll
  for (int it = 0; it < 5; ++it) {
    const int tT = (it < 3) ? 0 : ((it == 3) ? 1 : 2);
    const int tI = (it < 4) ? 0 : 1;
    short8 bb[2];
#pragma unroll
    for (int s = 0; s < 2; s++) bb[s] = *(const short8*)&Bc[(wave * 16 + l15) * ST + quad * 8 + 32 * s];
    f32x4 accT[4];
#pragma unroll
    for (int mt = 0; mt < 4; mt++) {
      accT[mt] = (f32x4){0.f, 0.f, 0.f, 0.f};
      if (mt - wave >= tT) {
#pragma unroll
        for (int s = 0; s < 2; s++) {
          short8 af = *(const short8*)&Br[(mt * 16 + l15) * ST + quad * 8 + 32 * s];
          accT[mt] = mfma16(af, bb[s], accT[mt]);
        }
      }
    }
    __syncthreads();  // all lanes done reading Br/Bc -> safe to overwrite
#pragma unroll
    for (int mt = 0; mt < 4; mt++) {
      if (mt - wave >= tI) {
#pragma unroll
        for (int r = 0; r < 4; r++) {
          int i = mt * 16 + quad * 4 + r, t = wave * 16 + l15;
          u16 v = f2b(accT[mt][r]);
          Br[i * ST + t] = v;
          Bc[t * ST + i] = v;
        }
      }
    }
    __syncthreads();  // T visible
    short8 tb[2];
#pragma unroll
    for (int s = 0; s < 2; s++) tb[s] = *(const short8*)&Bc[(wave * 16 + l15) * ST + quad * 8 + 32 * s];
#pragma unroll
    for (int mt = 0; mt < 4; mt++) {
      if (mt - wave >= tT) {
        f32x4 a;
#pragma unroll
        for (int r = 0; r < 4; r++) a[r] = b2f(Mc[(mt * 16 + quad * 4 + r) * ST + wave * 16 + l15]);
#pragma unroll
        for (int s = 0; s < 2; s++) {
          short8 af = *(const short8*)&Mc[(mt * 16 + l15) * ST + quad * 8 + 32 * s];
          a = mfma16(af, tb[s], a);
        }
#pragma unroll
        for (int r = 0; r < 4; r++) Mn[(mt * 16 + quad * 4 + r) * ST + wave * 16 + l15] = f2b(a[r]);
      } else {
#pragma unroll
        for (int r = 0; r < 4; r++)
          Mn[(mt * 16 + quad * 4 + r) * ST + wave * 16 + l15] =
              Mc[(mt * 16 + quad * 4 + r) * ST + wave * 16 + l15];
      }
    }
    u16* tmp = Mc; Mc = Mn; Mn = tmp;
  }
  __syncthreads();  // drain last M-update before P3 reuses slots

  // P3 (vectorized): Mb = Minv*diag(beta); XT = normalized K^T (pass0) / raw V^T
  // (pass1); KTg coalesced copy of normalized K^T.
  u16* XT = mats;
  u16* Mb = Mn;  // free slot after odd number of swaps
  for (int idx = tid; idx < 512; idx += 256) {
    int i = idx >> 3, t8 = (idx & 7) * 8;
    short8 m8 = *(const short8*)&Mc[i * ST + t8];
    short8 o8;
#pragma unroll
    for (int e = 0; e < 8; e++) o8[e] = (short)f2b(b2f((u16)m8[e]) * beta_s[t8 + e]);
    *(short8*)&Mb[i * ST + t8] = o8;
  }
  int tv = tid & 63, dk0 = (tid >> 6) * 32;  // lane->token row, wave->dk block
  for (int pass = 0; pass < 2; ++pass) {
    const u16* src = pass ? vn : kn;
    const u16* srow = src + (size_t)(b * Ln + l0 + tv) * Dn + h * 128 + dk0;
    float rsc = pass ? 1.f : rnk_s[tv];
#pragma unroll
    for (int s = 0; s < 4; s++) {
      short8 vv = *(const short8*)&srow[s * 8];
      if (!pass) vv = scale8(vv, rsc);
#pragma unroll
      for (int e = 0; e < 8; e++) XT[(dk0 + s * 8 + e) * ST + tv] = (u16)vv[e];
    }
    __syncthreads();
    if (pass == 0) {
#pragma unroll
      for (int it2 = 0; it2 < 4; it2++) {
        int idx = tid + it2 * 256;
        int dk = idx >> 3, t0 = (idx & 7) * 8;
        *(short8*)&KTg[(size_t)gid * 8192 + dk * 64 + t0] =
            *(const short8*)&XT[dk * ST + t0];
      }
    }
    u16* dst = pass ? Ug : W2g;
#pragma unroll
    for (int half = 0; half < 2; ++half) {
      int nt = wave + half * 4;
      short8 bx[2];
#pragma unroll
      for (int s = 0; s < 2; s++) bx[s] = *(const short8*)&XT[(nt * 16 + l15) * ST + quad * 8 + 32 * s];
#pragma unroll
      for (int mt = 0; mt < 4; mt++) {
        f32x4 a = {0.f, 0.f, 0.f, 0.f};
#pragma unroll
        for (int s = 0; s < 2; s++) {
          short8 af = *(const short8*)&Mb[(mt * 16 + l15) * ST + quad * 8 + 32 * s];
          a = mfma16(af, bx[s], a);
        }
#pragma unroll
        for (int r = 0; r < 4; r++)
          dst[(size_t)gid * 8192 + (size_t)(mt * 16 + quad * 4 + r) * 128 + nt * 16 + l15] = f2b(a[r]);
      }
    }
    __syncthreads();
  }
}

// ---------------- sequential chunk scan (per b,h and 16-wide v-slice) ----------------
struct Frg { short8 w2[4], qf[4], gf[2], k0[2], k1[2]; float u[4]; };

__global__ __launch_bounds__(256) void k_scan(
    const u16* __restrict__ Qg, const u16* __restrict__ W2g, const u16* __restrict__ Ug,
    const u16* __restrict__ Gg, const u16* __restrict__ KTg, u16* __restrict__ Og) {
  constexpr int SST = 136, DST = 104;
  __shared__ u16 Sb[16 * SST];  // S^T slice, bf16 shadow: [v][dk]
  __shared__ u16 Db[16 * DST];  // Delta^T slice: [v][t]
  int bh = blockIdx.x, sl = blockIdx.y;
  int b = bh >> 4, h = bh & 15, c0 = sl * 16;
  int tid = threadIdx.x, wave = tid >> 6, lane = tid & 63, quad = lane >> 4, l15 = lane & 15;
  for (int i = tid; i < 16 * SST; i += 256) Sb[i] = 0;
  f32x4 accS0 = {0.f, 0.f, 0.f, 0.f}, accS1 = {0.f, 0.f, 0.f, 0.f};  // fp32 master state
  __syncthreads();

  auto load_frags = [&](Frg& F, int ci) {
    size_t ck = (size_t)bh * NCK + ci;
    const u16* w2row = W2g + ck * 8192 + (size_t)(wave * 16 + l15) * 128;
    const u16* qrow = Qg + ck * 8192 + (size_t)(wave * 16 + l15) * 128;
#pragma unroll
    for (int s = 0; s < 4; s++) {
      F.w2[s] = *(const short8*)&w2row[quad * 8 + 32 * s];
      F.qf[s] = *(const short8*)&qrow[quad * 8 + 32 * s];
    }
    const u16* grow = Gg + ck * 4096 + (size_t)(wave * 16 + l15) * 64;
    const u16* kt0 = KTg + ck * 8192 + (size_t)(wave * 16 + l15) * 64;
    const u16* kt1 = KTg + ck * 8192 + (size_t)((wave + 4) * 16 + l15) * 64;
#pragma unroll
    for (int s = 0; s < 2; s++) {
      F.gf[s] = *(const short8*)&grow[quad * 8 + 32 * s];
      F.k0[s] = *(const short8*)&kt0[quad * 8 + 32 * s];
      F.k1[s] = *(const short8*)&kt1[quad * 8 + 32 * s];
    }
    const u16* urow = Ug + ck * 8192 + (size_t)(wave * 16 + quad * 4) * 128 + c0 + l15;
#pragma unroll
    for (int r = 0; r < 4; r++) F.u[r] = b2f(urow[(size_t)r * 128]);
  };

  auto compute = [&](const Frg& F, int ci) {
    f32x4 accT = {0.f, 0.f, 0.f, 0.f}, accO = {0.f, 0.f, 0.f, 0.f};
#pragma unroll
    for (int s = 0; s < 4; s++) {
      short8 sf = *(const short8*)&Sb[l15 * SST + quad * 8 + 32 * s];
      accT = mfma16(F.w2[s], sf, accT);   // W2 @ S0
      accO = mfma16(F.qf[s], sf, accO);   // Q @ S0
    }
#pragma unroll
    for (int r = 0; r < 4; r++) {
      float d = F.u[r] - accT[r];         // Delta = U - W2@S0
      Db[l15 * DST + wave * 16 + quad * 4 + r] = f2b(d);
    }
    __syncthreads();
#pragma unroll
    for (int s = 0; s < 2; s++) {
      short8 df = *(const short8*)&Db[l15 * DST + quad * 8 + 32 * s];
      accO = mfma16(F.gf[s], df, accO);   // O += tril(QK^T) @ Delta
      accS0 = mfma16(F.k0[s], df, accS0); // S += K^T @ Delta
      accS1 = mfma16(F.k1[s], df, accS1);
    }
    u16* orow = Og + (size_t)(b * Ln + ci * 64 + wave * 16 + quad * 4) * Dn + h * 128 + c0 + l15;
#pragma unroll
    for (int r = 0; r < 4; r++) orow[(size_t)r * Dn] = f2b(accO[r]);
#pragma unroll
    for (int r = 0; r < 4; r++) {
      Sb[l15 * SST + wave * 16 + quad * 4 + r] = f2b(accS0[r]);
      Sb[l15 * SST + (wave + 4) * 16 + quad * 4 + r] = f2b(accS1[r]);
    }
    __syncthreads();
  };

  Frg FA, FB;
  load_frags(FA, 0);
  for (int ci = 0; ci < NCK; ci += 2) {
    load_frags(FB, ci + 1);
    compute(FA, ci);
    if (ci + 2 < NCK) load_frags(FA, ci + 2);
    compute(FB, ci + 1);
  }
}

// ---------------- RMSNorm over head dim (vectorized: 2 rows/wave, 8B/lane) -------
__global__ void k_rms(const u16* __restrict__ Og, const float* __restrict__ w, u16* __restrict__ out) {
  int tid = threadIdx.x, wave = tid >> 6, lane = tid & 63;
  int half = lane >> 5, l32 = lane & 31;
  size_t row = (size_t)blockIdx.x * 8 + wave * 2 + half;
  const u16* p = Og + row * 128 + l32 * 4;
  u32 u0 = *(const u32*)&p[0], u1 = *(const u32*)&p[2];
  float x0 = b2f((u16)(u0 & 0xffff)), x1 = b2f((u16)(u0 >> 16));
  float x2 = b2f((u16)(u1 & 0xffff)), x3 = b2f((u16)(u1 >> 16));
  float ss = x0 * x0 + x1 * x1 + x2 * x2 + x3 * x3;
#pragma unroll
  for (int o = 16; o > 0; o >>= 1) ss += __shfl_xor(ss, o, 64);  // stays in 32-half
  float sc = rsqrtf(ss * (1.f / 128.f) + 1e-5f);
  float4 wv = *(const float4*)&w[l32 * 4];
  u32 o0 = (u32)f2b(x0 * sc * wv.x) | ((u32)f2b(x1 * sc * wv.y) << 16);
  u32 o1 = (u32)f2b(x2 * sc * wv.z) | ((u32)f2b(x3 * sc * wv.w) << 16);
  u32* d = (u32*)&out[row * 128 + l32 * 4];
  d[0] = o0; d[1] = o1;
}

// ---------------- host ----------------
extern "C" void kernel_launch(void* const* d_in, const int* in_sizes, int n_in,
                              void* d_out, int out_size, void* d_ws, size_t ws_size,
                              hipStream_t stream) {
  (void)in_sizes; (void)n_in; (void)out_size; (void)ws_size;
  const float* hs_f = (const float*)d_in[0];
  const float* Wq = (const float*)d_in[1];
  const float* Wk = (const float*)d_in[2];
  const float* Wv = (const float*)d_in[3];
  const float* Wb = (const float*)d_in[4];
  const float* onw = (const float*)d_in[5];
  const float* Wo = (const float*)d_in[6];

  char* ws = (char*)d_ws;
  size_t off = 0;
  auto alloc = [&](size_t bytes) -> void* {
    void* p = ws + off;
    off += (bytes + 255) & ~(size_t)255;
    return p;
  };
  const size_t WB = (size_t)2048 * 2048 * 2;
  const size_t XB = (size_t)4096 * 2048 * 2;
  u16* WqT = (u16*)alloc(WB);   // WqT|WkT|WvT contiguous => fused Bt [6144][2048]
  u16* WkT = (u16*)alloc(WB);
  u16* WvT = (u16*)alloc(WB);
  u16* WoT = (u16*)alloc(WB);
  u16* WbT = (u16*)alloc((size_t)16 * 2048 * 2);
  u16* hsb = (u16*)alloc(XB);
  u16* qn  = (u16*)alloc(XB);   // qn|kn|vn contiguous => fused C
  u16* kn  = (u16*)alloc(XB);
  u16* vn  = (u16*)alloc(XB);   // reused as O after precompute
  u16* W2g = (u16*)alloc((size_t)NCHUNKS * 8192 * 2);
  u16* Ug  = (u16*)alloc((size_t)NCHUNKS * 8192 * 2);
  u16* Gg  = (u16*)alloc((size_t)NCHUNKS * 4096 * 2);
  u16* KTg = (u16*)alloc((size_t)NCHUNKS * 8192 * 2);
  u16* Qg  = (u16*)alloc((size_t)NCHUNKS * 8192 * 2);  // normalized q, chunk layout
  float* beta_g = (float*)alloc((size_t)Bn * Hn * Ln * 4);
  u16* Og = vn;       // v dead after precompute
  u16* onorm = qn;    // q dead after precompute (scan reads Qg)

  // 0) fused front-end: weight transposes + hs downcast + Wb (one dispatch)
  PrepArgs pp;
  pp.wsrc[0] = Wq; pp.wdst[0] = WqT;
  pp.wsrc[1] = Wk; pp.wdst[1] = WkT;
  pp.wsrc[2] = Wv; pp.wdst[2] = WvT;
  pp.wsrc[3] = Wo; pp.wdst[3] = WoT;
  pp.wsrc[4] = Wb; pp.wdst[4] = WbT;
  pp.hs = hs_f; pp.hsb = hsb;
  hipLaunchKernelGGL(k_prep, dim3(8256), dim3(256), 0, stream, pp);

  // 1) beta for all heads (K-split, 256 blocks)
  hipLaunchKernelGGL(k_beta, dim3(Mrows / 16), dim3(256), 0, stream, hsb, WbT, beta_g);

  // 2) fused q/k/v projection: one 4096x6144x2048 GEMM, 256x384 tiles, grid-exact 256
  {
    Gemm2Args g2;
    g2.A = hsb; g2.Bt = WqT; g2.C = qn; g2.K = 2048;
    hipLaunchKernelGGL(k_gemm2, dim3(256), dim3(512), 0, stream, g2);
  }

  // 3) chunk precompute + fused l2-norm
  hipLaunchKernelGGL(k_pre, dim3(NCHUNKS), dim3(256), 0, stream,
                     beta_g, qn, kn, vn, W2g, Ug, Gg, KTg, Qg);

  // 4) sequential scan (reads normalized q from Qg chunk layout)
  hipLaunchKernelGGL(k_scan, dim3(32, 8), dim3(256), 0, stream,
                     Qg, W2g, Ug, Gg, KTg, Og);

  // 5) RMSNorm (2 rows/wave, 8B/lane)
  hipLaunchKernelGGL(k_rms, dim3(8192), dim3(256), 0, stream, Og, onw, onorm);

  // 6) output projection (fp32 out -> d_out), 4-phase 128x256 pipeline, grid 256
  {
    GemmoArgs go;
    go.A = onorm; go.Bt = WoT; go.C = (float*)d_out; go.K = 2048;
    hipLaunchKernelGGL(k_gemmo, dim3(256), dim3(512), 0, stream, go);
  }
}

// Round 13
// 408.954 us; speedup vs baseline: 1.0751x; 1.0022x over previous
//
#include <hip/hip_runtime.h>
#include <hip/hip_bf16.h>
#include <cstdint>

#define DEV static __device__ __forceinline__

typedef unsigned short u16;
typedef unsigned int u32;
typedef __attribute__((ext_vector_type(8))) short short8;
typedef __attribute__((ext_vector_type(4))) float f32x4;

constexpr int Bn = 2, Ln = 2048, Dn = 2048, Hn = 16;
constexpr int Mrows = Bn * Ln;          // 4096
constexpr int CHK = 64, NCK = Ln / CHK; // chunk=64, 32 chunks/seq
constexpr int NCHUNKS = Bn * Hn * NCK;  // 1024

DEV float b2f(u16 s) { union { float f; u32 u; } x; x.u = ((u32)s) << 16; return x.f; }
DEV u16 f2b(float f) {
  union { float f; u32 u; } x; x.f = f; u32 u = x.u;
  return (u16)((u + 0x7fffu + ((u >> 16) & 1u)) >> 16);  // RNE
}

DEV void cp16(const void* g, void* l) {
  __builtin_amdgcn_global_load_lds(
      (const __attribute__((address_space(1))) u32*)(unsigned long long)(g),
      (__attribute__((address_space(3))) u32*)(unsigned long long)(l), 16, 0, 0);
}

DEV f32x4 mfma16(short8 a, short8 b, f32x4 c) {
  return __builtin_amdgcn_mfma_f32_16x16x32_bf16(a, b, c, 0, 0, 0);
}

DEV short8 scale8(short8 v, float sc) {
  short8 o;
#pragma unroll
  for (int e = 0; e < 8; e++) o[e] = (short)f2b(b2f((u16)v[e]) * sc);
  return o;
}

// ---------------- fused front-end: weight transposes + hs downcast + Wb ---------
struct PrepArgs { const float* wsrc[5]; u16* wdst[5]; const float* hs; u16* hsb; };
__global__ __launch_bounds__(256) void k_prep(PrepArgs p) {
  __shared__ u16 tile[64 * 72];
  int bid = blockIdx.x, tid = threadIdx.x;
  if (bid < 4096) {
    int z = bid >> 10, t = bid & 1023;
    int r0 = (t >> 5) * 64, c0 = (t & 31) * 64;
    const float* src = p.wsrc[z];
    u16* dst = p.wdst[z];
    int lr = tid >> 2, lc = (tid & 3) * 16;
    const float* s = src + (size_t)(r0 + lr) * 2048 + c0 + lc;
#pragma unroll
    for (int i = 0; i < 4; i++) {
      float4 v = *(const float4*)(s + i * 4);
      tile[lr * 72 + lc + i * 4 + 0] = f2b(v.x);
      tile[lr * 72 + lc + i * 4 + 1] = f2b(v.y);
      tile[lr * 72 + lc + i * 4 + 2] = f2b(v.z);
      tile[lr * 72 + lc + i * 4 + 3] = f2b(v.w);
    }
    __syncthreads();
    int orr = tid >> 2, oc = (tid & 3) * 16;
    u16* d = dst + (size_t)(c0 + orr) * 2048 + r0 + oc;
    u16 buf[16];
#pragma unroll
    for (int e = 0; e < 16; e++) buf[e] = tile[(oc + e) * 72 + orr];
    *(short8*)(d) = *(short8*)buf;
    *(short8*)(d + 8) = *(short8*)(buf + 8);
  } else if (bid < 8192) {
    int i = (bid - 4096) * 256 + tid;  // exact: 4096*256 == Mrows*Dn/8
    const float4* s4 = (const float4*)(p.hs + (size_t)i * 8);
    float4 a = s4[0], b = s4[1];
    u16 o[8] = {f2b(a.x), f2b(a.y), f2b(a.z), f2b(a.w),
                f2b(b.x), f2b(b.y), f2b(b.z), f2b(b.w)};
    *(short8*)(p.hsb + (size_t)i * 8) = *(short8*)o;
  } else {
    // Wb 2048x16 -> WbT 16x2048, 32-row strip per block
    int r0 = (bid - 8192) * 32;
    int tx = tid & 31, ty = tid >> 5;  // 32x8
    for (int i = ty; i < 32; i += 8) {
      if (tx < 16) tile[i * 33 + tx] = f2b(p.wsrc[4][(size_t)(r0 + i) * 16 + tx]);
    }
    __syncthreads();
    for (int i = ty; i < 32; i += 8) {
      if (i < 16) p.wdst[4][(size_t)i * 2048 + r0 + tx] = tile[tx * 33 + i];
    }
  }
}

// ---------------- beta = sigmoid(hs @ Wb), K-split MFMA GEMV ----------------
__global__ __launch_bounds__(256) void k_beta(const u16* __restrict__ hs,
                                              const u16* __restrict__ WbT,
                                              float* __restrict__ beta_g) {
  __shared__ float part[256];  // [head][tokr]
  int tid = threadIdx.x, wave = tid >> 6, lane = tid & 63, quad = lane >> 4, l15 = lane & 15;
  int tok0 = blockIdx.x * 16;
  const u16* arow = hs + (size_t)(tok0 + l15) * Dn + wave * 512;   // A[m=l15][k-slice]
  const u16* brow = WbT + (size_t)l15 * Dn + wave * 512;           // B[n=head=l15][k-slice]
  f32x4 acc = {0.f, 0.f, 0.f, 0.f};
#pragma unroll
  for (int k = 0; k < 512; k += 32) {
    short8 af = *(const short8*)&arow[k + quad * 8];
    short8 bf = *(const short8*)&brow[k + quad * 8];
    acc = mfma16(af, bf, acc);
  }
  part[tid] = 0.f;
  __syncthreads();
#pragma unroll
  for (int r = 0; r < 4; r++) atomicAdd(&part[l15 * 16 + quad * 4 + r], acc[r]);
  __syncthreads();
  int h = tid >> 4, tr = tid & 15;
  int b = tok0 >> 11;
  int l = (tok0 + tr) & 2047;
  beta_g[(size_t)(b * Hn + h) * Ln + l] = 1.f / (1.f + __expf(-part[h * 16 + tr]));
}

// ---------------- fused QKV GEMM: 256x384 tile, 4-phase unit pipeline ----------------
// VERBATIM round-4 verified structure (120-123 us). FROZEN.
struct Gemm2Args { const u16* A; const u16* Bt; u16* C; int K; };

__global__ __launch_bounds__(512, 2) void k_gemm2(Gemm2Args g) {
  // A slots: 3 x 16384B at 0; B slots: 3 x 24576B at 49152. Total 122880B.
  __shared__ u16 ldsbuf[61440];
  const char* LB = (const char*)ldsbuf;
  const int K = g.K, NT = K / 64;
  const size_t Kb = (size_t)K * 2;
  int tid = threadIdx.x, wave = tid >> 6, lane = tid & 63;
  int quad = lane >> 4, l15 = lane & 15;
  int wm = wave >> 2, wn = wave & 3;  // 2M x 4N wave grid; per-wave C = 128x96

  // XCD-aware swizzle (256 % 8 == 0): each XCD gets a contiguous 32-block chunk
  int bid = blockIdx.x;
  int wg = (bid & 7) * 32 + (bid >> 3);
  int by = wg >> 4, bx = wg & 15;   // 16 x 16 tiles
  int m0 = by * 256, n0f = bx * 384;

  // staging: thread covers row r0 (+128/s); source col-block inverse-swizzled
  int r0 = tid >> 2;
  int cby = (((tid & 3) ^ ((tid >> 3) & 3)) * 16);
  const char* gA = (const char*)g.A + (size_t)(m0 + r0) * Kb + cby;
  const char* gB = (const char*)g.Bt + (size_t)(n0f + r0) * Kb + cby;

  auto stageA = [&](int slot, int t, int kh) {
    const char* src = gA + (size_t)t * 128 + kh * 64;
    u16* dst = &ldsbuf[slot * 8192 + tid * 8];
    cp16(src, dst);
    cp16(src + (size_t)128 * Kb, dst + 4096);
  };
  auto stageB = [&](int slot, int t, int kh) {
    const char* src = gB + (size_t)t * 128 + kh * 64;
    u16* dst = &ldsbuf[24576 + slot * 12288 + tid * 8];
    cp16(src, dst);
    cp16(src + (size_t)128 * Kb, dst + 4096);
    cp16(src + (size_t)256 * Kb, dst + 8192);
  };

  f32x4 acc0[4][6], acc1[4][6];
#pragma unroll
  for (int i = 0; i < 4; i++)
#pragma unroll
    for (int j = 0; j < 6; j++) {
      acc0[i][j] = (f32x4){0.f, 0.f, 0.f, 0.f};
      acc1[i][j] = (f32x4){0.f, 0.f, 0.f, 0.f};
    }

  // frag byte offsets within a unit: row*64 + swizzled slot*16
  int rsw = (l15 >> 1) & 3;
  int rA = (wm * 128 + l15) * 64 + ((quad ^ rsw) * 16);  // + mq*4096 + i*1024
  int rB = (wn * 96 + l15) * 64 + ((quad ^ rsw) * 16);   // + j*1024

  // prologue: stage tile 0 (units into slots 0,0,1,1)
  stageA(0, 0, 0);
  stageB(0, 0, 0);
  stageA(1, 0, 1);
  stageB(1, 0, 1);

  short8 bf[6];
  int u0 = 0;
  for (int t = 0; t < NT; ++t) {
    int u1 = u0 + 1; if (u1 == 3) u1 = 0;
    int u2 = u1 + 1; if (u2 == 3) u2 = 0;
    bool pf = (t + 1 < NT);
    const char* aK0 = LB + u0 * 16384;
    const char* aK1 = LB + u1 * 16384;
    const char* bK0 = LB + 49152 + u0 * 24576;
    const char* bK1 = LB + 49152 + u1 * 24576;

    // ---- phase 0: (mq=0, kh=0); stage A(t+1,0) -> u2 ----
    asm volatile("s_waitcnt vmcnt(5)" ::: "memory");
    __builtin_amdgcn_s_barrier();
    __builtin_amdgcn_sched_barrier(0);
    if (pf) stageA(u2, t + 1, 0);
    {
      short8 av[4];
#pragma unroll
      for (int i = 0; i < 4; i++) av[i] = *(const short8*)(aK0 + rA + i * 1024);
#pragma unroll
      for (int j = 0; j < 6; j++) bf[j] = *(const short8*)(bK0 + rB + j * 1024);
      __builtin_amdgcn_s_setprio(1);
#pragma unroll
      for (int i = 0; i < 4; i++)
#pragma unroll
        for (int j = 0; j < 6; j++) acc0[i][j] = mfma16(av[i], bf[j], acc0[i][j]);
      __builtin_amdgcn_s_setprio(0);
    }

    // ---- phase 1: (mq=1, kh=0); stage B(t+1,0) -> u2 ----
    asm volatile("s_waitcnt vmcnt(5)" ::: "memory");
    __builtin_amdgcn_s_barrier();
    __builtin_amdgcn_sched_barrier(0);
    if (pf) stageB(u2, t + 1, 0);
    {
      short8 av[4];
#pragma unroll
      for (int i = 0; i < 4; i++) av[i] = *(const short8*)(aK0 + rA + 4096 + i * 1024);
      __builtin_amdgcn_s_setprio(1);
#pragma unroll
      for (int i = 0; i < 4; i++)
#pragma unroll
        for (int j = 0; j < 6; j++) acc1[i][j] = mfma16(av[i], bf[j], acc1[i][j]);
      __builtin_amdgcn_s_setprio(0);
    }

    // ---- phase 2: (mq=0, kh=1); stage A(t+1,1) -> u0 ----
    if (t == NT - 1) asm volatile("s_waitcnt vmcnt(0)" ::: "memory");
    else asm volatile("s_waitcnt vmcnt(5)" ::: "memory");
    __builtin_amdgcn_s_barrier();
    __builtin_amdgcn_sched_barrier(0);
    if (pf) stageA(u0, t + 1, 1);
    {
      short8 av[4];
#pragma unroll
      for (int i = 0; i < 4; i++) av[i] = *(const short8*)(aK1 + rA + i * 1024);
#pragma unroll
      for (int j = 0; j < 6; j++) bf[j] = *(const short8*)(bK1 + rB + j * 1024);
      __builtin_amdgcn_s_setprio(1);
#pragma unroll
      for (int i = 0; i < 4; i++)
#pragma unroll
        for (int j = 0; j < 6; j++) acc0[i][j] = mfma16(av[i], bf[j], acc0[i][j]);
      __builtin_amdgcn_s_setprio(0);
    }

    // ---- phase 3: (mq=1, kh=1); stage B(t+1,1) -> u0 ----
    asm volatile("s_waitcnt vmcnt(5)" ::: "memory");
    __builtin_amdgcn_s_barrier();
    __builtin_amdgcn_sched_barrier(0);
    if (pf) stageB(u0, t + 1, 1);
    {
      short8 av[4];
#pragma unroll
      for (int i = 0; i < 4; i++) av[i] = *(const short8*)(aK1 + rA + 4096 + i * 1024);
      __builtin_amdgcn_s_setprio(1);
#pragma unroll
      for (int i = 0; i < 4; i++)
#pragma unroll
        for (int j = 0; j < 6; j++) acc1[i][j] = mfma16(av[i], bf[j], acc1[i][j]);
      __builtin_amdgcn_s_setprio(0);
    }

    u0 = u2;
  }

  // epilogue: per-fragment z selection across the q/k/v boundary
#pragma unroll
  for (int mq = 0; mq < 2; mq++) {
#pragma unroll
    for (int i = 0; i < 4; i++)
#pragma unroll
      for (int j = 0; j < 6; j++) {
        f32x4 a = mq ? acc1[i][j] : acc0[i][j];
        int row = m0 + wm * 128 + mq * 64 + i * 16 + quad * 4;
        int colg = n0f + wn * 96 + j * 16;
        int z = colg >> 11;
        u16* Cz = g.C + (size_t)z * ((size_t)Mrows * 2048);
        int col = (colg & 2047) + l15;
#pragma unroll
        for (int r = 0; r < 4; r++) {
          float v = a[r];
          if (z == 2) v = v / (1.f + __expf(-v));  // silu (v-projection)
          Cz[(size_t)(row + r) * 2048 + col] = f2b(v);
        }
      }
  }
}

// ---------------- Wo GEMM: 128x256 tile, 4-phase unit pipeline, f32 out ----------
struct GemmoArgs { const u16* A; const u16* Bt; float* C; int K; };

__global__ __launch_bounds__(512, 2) void k_gemmo(GemmoArgs g) {
  // A slots: 3 x 8192B at 0; B slots: 3 x 16384B at 24576. Total 73728B.
  __shared__ u16 ldsbuf[36864];
  const char* LB = (const char*)ldsbuf;
  const int K = g.K, NT = K / 64;
  const size_t Kb = (size_t)K * 2;
  int tid = threadIdx.x, wave = tid >> 6, lane = tid & 63;
  int quad = lane >> 4, l15 = lane & 15;
  int wm = wave >> 2, wn = wave & 3;  // 2M x 4N; per-wave C = 64x64

  // XCD swizzle: chunk = one bx column (B-panel 2MB L2-resident per XCD)
  int bid = blockIdx.x;
  int wg = (bid & 7) * 32 + (bid >> 3);
  int bx = wg >> 5, by = wg & 31;
  int m0 = by * 128, n0 = bx * 256;

  int r0 = tid >> 2;
  int cby = (((tid & 3) ^ ((tid >> 3) & 3)) * 16);
  const char* gA = (const char*)g.A + (size_t)(m0 + r0) * Kb + cby;
  const char* gB = (const char*)g.Bt + (size_t)(n0 + r0) * Kb + cby;

  auto stageA = [&](int slot, int t, int kh) {
    const char* src = gA + (size_t)t * 128 + kh * 64;
    cp16(src, &ldsbuf[slot * 4096 + tid * 8]);
  };
  auto stageB = [&](int slot, int t, int kh) {
    const char* src = gB + (size_t)t * 128 + kh * 64;
    u16* dst = &ldsbuf[12288 + slot * 8192 + tid * 8];
    cp16(src, dst);
    cp16(src + (size_t)128 * Kb, dst + 4096);
  };

  f32x4 acc[4][4];
#pragma unroll
  for (int i = 0; i < 4; i++)
#pragma unroll
    for (int j = 0; j < 4; j++) acc[i][j] = (f32x4){0.f, 0.f, 0.f, 0.f};

  int rsw = (l15 >> 1) & 3;
  int rA = (wm * 64 + l15) * 64 + ((quad ^ rsw) * 16);  // + i*1024
  int rB = (wn * 64 + l15) * 64 + ((quad ^ rsw) * 16);  // + (jh*2+j)*1024

  stageA(0, 0, 0);
  stageB(0, 0, 0);
  stageA(1, 0, 1);
  stageB(1, 0, 1);

  short8 av[4];
  int u0 = 0;
  for (int t = 0; t < NT; ++t) {
    int u1 = u0 + 1; if (u1 == 3) u1 = 0;
    int u2 = u1 + 1; if (u2 == 3) u2 = 0;
    bool pf = (t + 1 < NT);
    const char* aK0 = LB + u0 * 8192;
    const char* aK1 = LB + u1 * 8192;
    const char* bK0 = LB + 24576 + u0 * 16384;
    const char* bK1 = LB + 24576 + u1 * 16384;

    // ---- phase 0: (kh0, jh0); stage A(t+1,0) -> u2 ----
    asm volatile("s_waitcnt vmcnt(3)" ::: "memory");
    __builtin_amdgcn_s_barrier();
    __builtin_amdgcn_sched_barrier(0);
    if (pf) stageA(u2, t + 1, 0);
    {
      short8 bv[2];
#pragma unroll
      for (int i = 0; i < 4; i++) av[i] = *(const short8*)(aK0 + rA + i * 1024);
#pragma unroll
      for (int j = 0; j < 2; j++) bv[j] = *(const short8*)(bK0 + rB + j * 1024);
      __builtin_amdgcn_s_setprio(1);
#pragma unroll
      for (int i = 0; i < 4; i++)
#pragma unroll
        for (int j = 0; j < 2; j++) acc[i][j] = mfma16(av[i], bv[j], acc[i][j]);
      __builtin_amdgcn_s_setprio(0);
    }

    // ---- phase 1: (kh0, jh1); stage B(t+1,0) -> u2 ----
    asm volatile("s_waitcnt vmcnt(3)" ::: "memory");
    __builtin_amdgcn_s_barrier();
    __builtin_amdgcn_sched_barrier(0);
    if (pf) stageB(u2, t + 1, 0);
    {
      short8 bv[2];
#pragma unroll
      for (int j = 0; j < 2; j++) bv[j] = *(const short8*)(bK0 + rB + (2 + j) * 1024);
      __builtin_amdgcn_s_setprio(1);
#pragma unroll
      for (int i = 0; i < 4; i++)
#pragma unroll
        for (int j = 0; j < 2; j++) acc[i][2 + j] = mfma16(av[i], bv[j], acc[i][2 + j]);
      __builtin_amdgcn_s_setprio(0);
    }

    // ---- phase 2: (kh1, jh0); stage A(t+1,1) -> u0 ----
    if (t == NT - 1) asm volatile("s_waitcnt vmcnt(0)" ::: "memory");
    else asm volatile("s_waitcnt vmcnt(3)" ::: "memory");
    __builtin_amdgcn_s_barrier();
    __builtin_amdgcn_sched_barrier(0);
    if (pf) stageA(u0, t + 1, 1);
    {
      short8 bv[2];
#pragma unroll
      for (int i = 0; i < 4; i++) av[i] = *(const short8*)(aK1 + rA + i * 1024);
#pragma unroll
      for (int j = 0; j < 2; j++) bv[j] = *(const short8*)(bK1 + rB + j * 1024);
      __builtin_amdgcn_s_setprio(1);
#pragma unroll
      for (int i = 0; i < 4; i++)
#pragma unroll
        for (int j = 0; j < 2; j++) acc[i][j] = mfma16(av[i], bv[j], acc[i][j]);
      __builtin_amdgcn_s_setprio(0);
    }

    // ---- phase 3: (kh1, jh1); stage B(t+1,1) -> u0 ----
    asm volatile("s_waitcnt vmcnt(3)" ::: "memory");
    __builtin_amdgcn_s_barrier();
    __builtin_amdgcn_sched_barrier(0);
    if (pf) stageB(u0, t + 1, 1);
    {
      short8 bv[2];
#pragma unroll
      for (int j = 0; j < 2; j++) bv[j] = *(const short8*)(bK1 + rB + (2 + j) * 1024);
      __builtin_amdgcn_s_setprio(1);
#pragma unroll
      for (int i = 0; i < 4; i++)
#pragma unroll
        for (int j = 0; j < 2; j++) acc[i][2 + j] = mfma16(av[i], bv[j], acc[i][2 + j]);
      __builtin_amdgcn_s_setprio(0);
    }

    u0 = u2;
  }

  // epilogue: f32 out
#pragma unroll
  for (int i = 0; i < 4; i++)
#pragma unroll
    for (int j = 0; j < 4; j++) {
      int row = m0 + wm * 64 + i * 16 + quad * 4;
      int col = n0 + wn * 64 + j * 16 + l15;
#pragma unroll
      for (int r = 0; r < 4; r++)
        g.C[(size_t)(row + r) * 2048 + col] = acc[i][j][r];
    }
}

// ---------------- per-chunk precompute + FUSED l2-norm ----------------
constexpr int ST = 72;
__global__ __launch_bounds__(256, 4) void k_pre(
    const float* __restrict__ beta_g,
    const u16* __restrict__ qn, const u16* __restrict__ kn, const u16* __restrict__ vn,
    u16* __restrict__ W2g, u16* __restrict__ Ug, u16* __restrict__ Gg, u16* __restrict__ KTg,
    u16* __restrict__ Qg) {
  __shared__ float beta_s[64];
  __shared__ float rnk_s[64], rnq_s[64];
  __shared__ u16 mats[4 * 64 * ST];
  int gid = blockIdx.x;
  int c = gid & 31, h = (gid >> 5) & 15, b = gid >> 9;
  int tid = threadIdx.x;
  int l0 = c * 64;

  int wave = tid >> 6, lane = tid & 63, quad = lane >> 4, l15 = lane & 15;
  u16 *Br = mats, *Bc = mats + 64 * ST, *M0 = mats + 2 * 64 * ST, *M1 = mats + 3 * 64 * ST;

  // row norms for this block's 64 tokens (rows wave*16+l15, 4-lane spread)
  short8 bfr[4], qfr[4];
  {
    int row = wave * 16 + l15;
    const u16* krow = kn + (size_t)(b * Ln + l0 + row) * Dn + h * 128;
    const u16* qrow = qn + (size_t)(b * Ln + l0 + row) * Dn + h * 128;
    float ssk = 0.f, ssq = 0.f;
#pragma unroll
    for (int s = 0; s < 4; s++) {
      bfr[s] = *(const short8*)&krow[quad * 8 + 32 * s];
      qfr[s] = *(const short8*)&qrow[quad * 8 + 32 * s];
#pragma unroll
      for (int e = 0; e < 8; e++) {
        float xk = b2f((u16)bfr[s][e]), xq = b2f((u16)qfr[s][e]);
        ssk += xk * xk; ssq += xq * xq;
      }
    }
    ssk += __shfl_xor(ssk, 16, 64); ssk += __shfl_xor(ssk, 32, 64);
    ssq += __shfl_xor(ssq, 16, 64); ssq += __shfl_xor(ssq, 32, 64);
    float rk = 1.f / fmaxf(sqrtf(ssk), 1e-12f);
    float rq = 0.08838834764831845f / fmaxf(sqrtf(ssq), 1e-12f);  // dh^-0.5 folded
    if (quad == 0) { rnk_s[row] = rk; rnq_s[row] = rq; }
#pragma unroll
    for (int s = 0; s < 4; s++) {
      bfr[s] = scale8(bfr[s], rk);
      *(short8*)&Qg[(size_t)gid * 8192 + (size_t)row * 128 + quad * 8 + 32 * s] =
          scale8(qfr[s], rq);
    }
  }
  if (tid < 64) beta_s[tid] = beta_g[(size_t)(b * Hn + h) * Ln + l0 + tid];
  __syncthreads();

  // P1: A_full = Kn Kn^T, G = tril(Qn Kn^T); B=-strict_tril(diag(beta)A), M=I+B
  {
#pragma unroll
    for (int mt = 0; mt < 4; ++mt) {
      const u16* arow_k = kn + (size_t)(b * Ln + l0 + mt * 16 + l15) * Dn + h * 128;
      const u16* arow_q = qn + (size_t)(b * Ln + l0 + mt * 16 + l15) * Dn + h * 128;
      float rkA = rnk_s[mt * 16 + l15], rqA = rnq_s[mt * 16 + l15];
      f32x4 accA = {0.f, 0.f, 0.f, 0.f}, accG = {0.f, 0.f, 0.f, 0.f};
#pragma unroll
      for (int s = 0; s < 4; s++) {
        short8 ak = scale8(*(const short8*)&arow_k[quad * 8 + 32 * s], rkA);
        short8 aq = scale8(*(const short8*)&arow_q[quad * 8 + 32 * s], rqA);
        accA = mfma16(ak, bfr[s], accA);
        accG = mfma16(aq, bfr[s], accG);
      }
      int t = wave * 16 + l15;
#pragma unroll
      for (int r = 0; r < 4; r++) {
        int i = mt * 16 + quad * 4 + r;
        u16 nb = f2b((t < i) ? -beta_s[i] * accA[r] : 0.f);
        Br[i * ST + t] = nb;
        Bc[t * ST + i] = nb;
        M0[i * ST + t] = (t == i) ? f2b(1.f) : nb;
        Gg[(size_t)gid * 4096 + (size_t)i * 64 + t] = f2b((t <= i) ? accG[r] : 0.f);
      }
    }
  }
  __syncthreads();

  // P2: Minv = (I+B)(I+B^2)(I+B^4)(I+B^8)(I+B^16)(I+B^32)
  u16 *Mc = M0, *Mn = M1;
#pragma unroll
  for (int it = 0; it < 5; ++it) {
    const int tT = (it < 3) ? 0 : ((it == 3) ? 1 : 2);
    const int tI = (it < 4) ? 0 : 1;
    short8 bb[2];
#pragma unroll
    for (int s = 0; s < 2; s++) bb[s] = *(const short8*)&Bc[(wave * 16 + l15) * ST + quad * 8 + 32 * s];
    f32x4 accT[4];
#pragma unroll
    for (int mt = 0; mt < 4; mt++) {
      accT[mt] = (f32x4){0.f, 0.f, 0.f, 0.f};
      if (mt - wave >= tT) {
#pragma unroll
        for (int s = 0; s < 2; s++) {
          short8 af = *(const short8*)&Br[(mt * 16 + l15) * ST + quad * 8 + 32 * s];
          accT[mt] = mfma16(af, bb[s], accT[mt]);
        }
      }
    }
    __syncthreads();  // all lanes done reading Br/Bc -> safe to overwrite
#pragma unroll
    for (int mt = 0; mt < 4; mt++) {
      if (mt - wave >= tI) {
#pragma unroll
        for (int r = 0; r < 4; r++) {
          int i = mt * 16 + quad * 4 + r, t = wave * 16 + l15;
          u16 v = f2b(accT[mt][r]);
          Br[i * ST + t] = v;
          Bc[t * ST + i] = v;
        }
      }
    }
    __syncthreads();  // T visible
    short8 tb[2];
#pragma unroll
    for (int s = 0; s < 2; s++) tb[s] = *(const short8*)&Bc[(wave * 16 + l15) * ST + quad * 8 + 32 * s];
#pragma unroll
    for (int mt = 0; mt < 4; mt++) {
      if (mt - wave >= tT) {
        f32x4 a;
#pragma unroll
        for (int r = 0; r < 4; r++) a[r] = b2f(Mc[(mt * 16 + quad * 4 + r) * ST + wave * 16 + l15]);
#pragma unroll
        for (int s = 0; s < 2; s++) {
          short8 af = *(const short8*)&Mc[(mt * 16 + l15) * ST + quad * 8 + 32 * s];
          a = mfma16(af, tb[s], a);
        }
#pragma unroll
        for (int r = 0; r < 4; r++) Mn[(mt * 16 + quad * 4 + r) * ST + wave * 16 + l15] = f2b(a[r]);
      } else {
#pragma unroll
        for (int r = 0; r < 4; r++)
          Mn[(mt * 16 + quad * 4 + r) * ST + wave * 16 + l15] =
              Mc[(mt * 16 + quad * 4 + r) * ST + wave * 16 + l15];
      }
    }
    u16* tmp = Mc; Mc = Mn; Mn = tmp;
  }
  __syncthreads();  // drain last M-update before P3 reuses slots

  // P3 (vectorized): Mb = Minv*diag(beta); XT = normalized K^T (pass0) / raw V^T
  // (pass1); KTg coalesced copy of normalized K^T.
  u16* XT = mats;
  u16* Mb = Mn;  // free slot after odd number of swaps
  for (int idx = tid; idx < 512; idx += 256) {
    int i = idx >> 3, t8 = (idx & 7) * 8;
    short8 m8 = *(const short8*)&Mc[i * ST + t8];
    short8 o8;
#pragma unroll
    for (int e = 0; e < 8; e++) o8[e] = (short)f2b(b2f((u16)m8[e]) * beta_s[t8 + e]);
    *(short8*)&Mb[i * ST + t8] = o8;
  }
  int tv = tid & 63, dk0 = (tid >> 6) * 32;  // lane->token row, wave->dk block
  for (int pass = 0; pass < 2; ++pass) {
    const u16* src = pass ? vn : kn;
    const u16* srow = src + (size_t)(b * Ln + l0 + tv) * Dn + h * 128 + dk0;
    float rsc = pass ? 1.f : rnk_s[tv];
#pragma unroll
    for (int s = 0; s < 4; s++) {
      short8 vv = *(const short8*)&srow[s * 8];
      if (!pass) vv = scale8(vv, rsc);
#pragma unroll
      for (int e = 0; e < 8; e++) XT[(dk0 + s * 8 + e) * ST + tv] = (u16)vv[e];
    }
    __syncthreads();
    if (pass == 0) {
#pragma unroll
      for (int it2 = 0; it2 < 4; it2++) {
        int idx = tid + it2 * 256;
        int dk = idx >> 3, t0 = (idx & 7) * 8;
        *(short8*)&KTg[(size_t)gid * 8192 + dk * 64 + t0] =
            *(const short8*)&XT[dk * ST + t0];
      }
    }
    u16* dst = pass ? Ug : W2g;
#pragma unroll
    for (int half = 0; half < 2; ++half) {
      int nt = wave + half * 4;
      short8 bx[2];
#pragma unroll
      for (int s = 0; s < 2; s++) bx[s] = *(const short8*)&XT[(nt * 16 + l15) * ST + quad * 8 + 32 * s];
#pragma unroll
      for (int mt = 0; mt < 4; mt++) {
        f32x4 a = {0.f, 0.f, 0.f, 0.f};
#pragma unroll
        for (int s = 0; s < 2; s++) {
          short8 af = *(const short8*)&Mb[(mt * 16 + l15) * ST + quad * 8 + 32 * s];
          a = mfma16(af, bx[s], a);
        }
#pragma unroll
        for (int r = 0; r < 4; r++)
          dst[(size_t)gid * 8192 + (size_t)(mt * 16 + quad * 4 + r) * 128 + nt * 16 + l15] = f2b(a[r]);
      }
    }
    __syncthreads();
  }
}

// ---------------- sequential chunk scan (per b,h and 16-wide v-slice) ----------------
// T1 XCD swizzle: 1D grid 256, bijective chunking groups the 8 v-slices of each bh
// (which read IDENTICAL W2g/Gg/KTg/Qg streams, ~2.3MB/bh) onto one XCD -> 7/8
// readers hit the local 4MB L2 instead of L3. Pure index remap; output identical.
struct Frg { short8 w2[4], qf[4], gf[2], k0[2], k1[2]; float u[4]; };

__global__ __launch_bounds__(256) void k_scan(
    const u16* __restrict__ Qg, const u16* __restrict__ W2g, const u16* __restrict__ Ug,
    const u16* __restrict__ Gg, const u16* __restrict__ KTg, u16* __restrict__ Og) {
  constexpr int SST = 136, DST = 104;
  __shared__ u16 Sb[16 * SST];  // S^T slice, bf16 shadow: [v][dk]
  __shared__ u16 Db[16 * DST];  // Delta^T slice: [v][t]
  int bid = blockIdx.x;
  int lin = (bid & 7) * 32 + (bid >> 3);  // XCD chunk: 4 bh x 8 slices per XCD
  int bh = lin >> 3, sl = lin & 7;
  int b = bh >> 4, h = bh & 15, c0 = sl * 16;
  int tid = threadIdx.x, wave = tid >> 6, lane = tid & 63, quad = lane >> 4, l15 = lane & 15;
  for (int i = tid; i < 16 * SST; i += 256) Sb[i] = 0;
  f32x4 accS0 = {0.f, 0.f, 0.f, 0.f}, accS1 = {0.f, 0.f, 0.f, 0.f};  // fp32 master state
  __syncthreads();

  auto load_frags = [&](Frg& F, int ci) {
    size_t ck = (size_t)bh * NCK + ci;
    const u16* w2row = W2g + ck * 8192 + (size_t)(wave * 16 + l15) * 128;
    const u16* qrow = Qg + ck * 8192 + (size_t)(wave * 16 + l15) * 128;
#pragma unroll
    for (int s = 0; s < 4; s++) {
      F.w2[s] = *(const short8*)&w2row[quad * 8 + 32 * s];
      F.qf[s] = *(const short8*)&qrow[quad * 8 + 32 * s];
    }
    const u16* grow = Gg + ck * 4096 + (size_t)(wave * 16 + l15) * 64;
    const u16* kt0 = KTg + ck * 8192 + (size_t)(wave * 16 + l15) * 64;
    const u16* kt1 = KTg + ck * 8192 + (size_t)((wave + 4) * 16 + l15) * 64;
#pragma unroll
    for (int s = 0; s < 2; s++) {
      F.gf[s] = *(const short8*)&grow[quad * 8 + 32 * s];
      F.k0[s] = *(const short8*)&kt0[quad * 8 + 32 * s];
      F.k1[s] = *(const short8*)&kt1[quad * 8 + 32 * s];
    }
    const u16* urow = Ug + ck * 8192 + (size_t)(wave * 16 + quad * 4) * 128 + c0 + l15;
#pragma unroll
    for (int r = 0; r < 4; r++) F.u[r] = b2f(urow[(size_t)r * 128]);
  };

  auto compute = [&](const Frg& F, int ci) {
    f32x4 accT = {0.f, 0.f, 0.f, 0.f}, accO = {0.f, 0.f, 0.f, 0.f};
#pragma unroll
    for (int s = 0; s < 4; s++) {
      short8 sf = *(const short8*)&Sb[l15 * SST + quad * 8 + 32 * s];
      accT = mfma16(F.w2[s], sf, accT);   // W2 @ S0
      accO = mfma16(F.qf[s], sf, accO);   // Q @ S0
    }
#pragma unroll
    for (int r = 0; r < 4; r++) {
      float d = F.u[r] - accT[r];         // Delta = U - W2@S0
      Db[l15 * DST + wave * 16 + quad * 4 + r] = f2b(d);
    }
    __syncthreads();
#pragma unroll
    for (int s = 0; s < 2; s++) {
      short8 df = *(const short8*)&Db[l15 * DST + quad * 8 + 32 * s];
      accO = mfma16(F.gf[s], df, accO);   // O += tril(QK^T) @ Delta
      accS0 = mfma16(F.k0[s], df, accS0); // S += K^T @ Delta
      accS1 = mfma16(F.k1[s], df, accS1);
    }
    u16* orow = Og + (size_t)(b * Ln + ci * 64 + wave * 16 + quad * 4) * Dn + h * 128 + c0 + l15;
#pragma unroll
    for (int r = 0; r < 4; r++) orow[(size_t)r * Dn] = f2b(accO[r]);
#pragma unroll
    for (int r = 0; r < 4; r++) {
      Sb[l15 * SST + wave * 16 + quad * 4 + r] = f2b(accS0[r]);
      Sb[l15 * SST + (wave + 4) * 16 + quad * 4 + r] = f2b(accS1[r]);
    }
    __syncthreads();
  };

  Frg FA, FB;
  load_frags(FA, 0);
  for (int ci = 0; ci < NCK; ci += 2) {
    load_frags(FB, ci + 1);
    compute(FA, ci);
    if (ci + 2 < NCK) load_frags(FA, ci + 2);
    compute(FB, ci + 1);
  }
}

// ---------------- RMSNorm over head dim (vectorized: 2 rows/wave, 8B/lane) -------
__global__ void k_rms(const u16* __restrict__ Og, const float* __restrict__ w, u16* __restrict__ out) {
  int tid = threadIdx.x, wave = tid >> 6, lane = tid & 63;
  int half = lane >> 5, l32 = lane & 31;
  size_t row = (size_t)blockIdx.x * 8 + wave * 2 + half;
  const u16* p = Og + row * 128 + l32 * 4;
  u32 u0 = *(const u32*)&p[0], u1 = *(const u32*)&p[2];
  float x0 = b2f((u16)(u0 & 0xffff)), x1 = b2f((u16)(u0 >> 16));
  float x2 = b2f((u16)(u1 & 0xffff)), x3 = b2f((u16)(u1 >> 16));
  float ss = x0 * x0 + x1 * x1 + x2 * x2 + x3 * x3;
#pragma unroll
  for (int o = 16; o > 0; o >>= 1) ss += __shfl_xor(ss, o, 64);  // stays in 32-half
  float sc = rsqrtf(ss * (1.f / 128.f) + 1e-5f);
  float4 wv = *(const float4*)&w[l32 * 4];
  u32 o0 = (u32)f2b(x0 * sc * wv.x) | ((u32)f2b(x1 * sc * wv.y) << 16);
  u32 o1 = (u32)f2b(x2 * sc * wv.z) | ((u32)f2b(x3 * sc * wv.w) << 16);
  u32* d = (u32*)&out[row * 128 + l32 * 4];
  d[0] = o0; d[1] = o1;
}

// ---------------- host ----------------
extern "C" void kernel_launch(void* const* d_in, const int* in_sizes, int n_in,
                              void* d_out, int out_size, void* d_ws, size_t ws_size,
                              hipStream_t stream) {
  (void)in_sizes; (void)n_in; (void)out_size; (void)ws_size;
  const float* hs_f = (const float*)d_in[0];
  const float* Wq = (const float*)d_in[1];
  const float* Wk = (const float*)d_in[2];
  const float* Wv = (const float*)d_in[3];
  const float* Wb = (const float*)d_in[4];
  const float* onw = (const float*)d_in[5];
  const float* Wo = (const float*)d_in[6];

  char* ws = (char*)d_ws;
  size_t off = 0;
  auto alloc = [&](size_t bytes) -> void* {
    void* p = ws + off;
    off += (bytes + 255) & ~(size_t)255;
    return p;
  };
  const size_t WB = (size_t)2048 * 2048 * 2;
  const size_t XB = (size_t)4096 * 2048 * 2;
  u16* WqT = (u16*)alloc(WB);   // WqT|WkT|WvT contiguous => fused Bt [6144][2048]
  u16* WkT = (u16*)alloc(WB);
  u16* WvT = (u16*)alloc(WB);
  u16* WoT = (u16*)alloc(WB);
  u16* WbT = (u16*)alloc((size_t)16 * 2048 * 2);
  u16* hsb = (u16*)alloc(XB);
  u16* qn  = (u16*)alloc(XB);   // qn|kn|vn contiguous => fused C
  u16* kn  = (u16*)alloc(XB);
  u16* vn  = (u16*)alloc(XB);   // reused as O after precompute
  u16* W2g = (u16*)alloc((size_t)NCHUNKS * 8192 * 2);
  u16* Ug  = (u16*)alloc((size_t)NCHUNKS * 8192 * 2);
  u16* Gg  = (u16*)alloc((size_t)NCHUNKS * 4096 * 2);
  u16* KTg = (u16*)alloc((size_t)NCHUNKS * 8192 * 2);
  u16* Qg  = (u16*)alloc((size_t)NCHUNKS * 8192 * 2);  // normalized q, chunk layout
  float* beta_g = (float*)alloc((size_t)Bn * Hn * Ln * 4);
  u16* Og = vn;       // v dead after precompute
  u16* onorm = qn;    // q dead after precompute (scan reads Qg)

  // 0) fused front-end: weight transposes + hs downcast + Wb (one dispatch)
  PrepArgs pp;
  pp.wsrc[0] = Wq; pp.wdst[0] = WqT;
  pp.wsrc[1] = Wk; pp.wdst[1] = WkT;
  pp.wsrc[2] = Wv; pp.wdst[2] = WvT;
  pp.wsrc[3] = Wo; pp.wdst[3] = WoT;
  pp.wsrc[4] = Wb; pp.wdst[4] = WbT;
  pp.hs = hs_f; pp.hsb = hsb;
  hipLaunchKernelGGL(k_prep, dim3(8256), dim3(256), 0, stream, pp);

  // 1) beta for all heads (K-split, 256 blocks)
  hipLaunchKernelGGL(k_beta, dim3(Mrows / 16), dim3(256), 0, stream, hsb, WbT, beta_g);

  // 2) fused q/k/v projection: one 4096x6144x2048 GEMM, 256x384 tiles, grid-exact 256
  {
    Gemm2Args g2;
    g2.A = hsb; g2.Bt = WqT; g2.C = qn; g2.K = 2048;
    hipLaunchKernelGGL(k_gemm2, dim3(256), dim3(512), 0, stream, g2);
  }

  // 3) chunk precompute + fused l2-norm
  hipLaunchKernelGGL(k_pre, dim3(NCHUNKS), dim3(256), 0, stream,
                     beta_g, qn, kn, vn, W2g, Ug, Gg, KTg, Qg);

  // 4) sequential scan (XCD-grouped: 8 slices of each bh share one XCD's L2)
  hipLaunchKernelGGL(k_scan, dim3(256), dim3(256), 0, stream,
                     Qg, W2g, Ug, Gg, KTg, Og);

  // 5) RMSNorm (2 rows/wave, 8B/lane)
  hipLaunchKernelGGL(k_rms, dim3(8192), dim3(256), 0, stream, Og, onw, onorm);

  // 6) output projection (fp32 out -> d_out), 4-phase 128x256 pipeline, grid 256
  {
    GemmoArgs go;
    go.A = onorm; go.Bt = WoT; go.C = (float*)d_out; go.K = 2048;
    hipLaunchKernelGGL(k_gemmo, dim3(256), dim3(512), 0, stream, go);
  }
}